// Round 4
// baseline (1056.478 us; speedup 1.0000x reference)
//
#include <hip/hip_runtime.h>

// ---------------- types / helpers ----------------
typedef __attribute__((ext_vector_type(8))) short bf16x8;   // 8 bf16 (4 VGPRs)
typedef __attribute__((ext_vector_type(4))) float f32x4;    // MFMA accum
typedef __attribute__((ext_vector_type(8))) unsigned short u16x8;

#define D_MODEL 2048
#define NH 16
#define HD 128
#define SKV 3072
#define QK_SCALE 0.08838834764831845f  // 128^-0.5

__device__ __forceinline__ unsigned short f2bf(float f) {
  unsigned int u = __float_as_uint(f);
  u += 0x7fffu + ((u >> 16) & 1u);     // RNE, finite inputs only
  return (unsigned short)(u >> 16);
}

typedef __attribute__((address_space(1))) void as1_void;
typedef __attribute__((address_space(3))) void as3_void;
__device__ __forceinline__ void gload_lds16(const void* g, void* l) {
  __builtin_amdgcn_global_load_lds((as1_void*)g, (as3_void*)l, 16, 0, 0);
}

#define MFMA16(a, b, c) __builtin_amdgcn_mfma_f32_16x16x32_bf16((a), (b), (c), 0, 0, 0)

// ---------------- weight convert (optionally scaled) ----------------
__global__ __launch_bounds__(256) void cvt_w_kernel(
    const float* __restrict__ src, unsigned short* __restrict__ dst,
    float scale, int n8) {
  int i = blockIdx.x * 256 + threadIdx.x;
  if (i >= n8) return;
  const float4* s = (const float4*)src + (size_t)i * 2;
  float4 a = s[0], b = s[1];
  u16x8 r;
  r[0] = f2bf(a.x * scale); r[1] = f2bf(a.y * scale);
  r[2] = f2bf(a.z * scale); r[3] = f2bf(a.w * scale);
  r[4] = f2bf(b.x * scale); r[5] = f2bf(b.y * scale);
  r[6] = f2bf(b.z * scale); r[7] = f2bf(b.w * scale);
  *((u16x8*)dst + i) = r;
}

// ---------------- LayerNorm -> bf16 (with row remap for K concat) ----------------
__global__ __launch_bounds__(256) void ln_kernel(
    const float* __restrict__ x, const float* __restrict__ gw,
    const float* __restrict__ bw, unsigned short* __restrict__ out,
    int spb, int orpb, int obase) {
  const int row = blockIdx.x;
  const int t = threadIdx.x;
  const int b = row / spb, s = row - b * spb;
  const float* xr = x + (size_t)row * D_MODEL;
  unsigned short* orow = out + ((size_t)b * orpb + obase + s) * D_MODEL;

  float4 v0 = *(const float4*)(xr + t * 8);
  float4 v1 = *(const float4*)(xr + t * 8 + 4);
  float sum = v0.x + v0.y + v0.z + v0.w + v1.x + v1.y + v1.z + v1.w;
  float sq  = v0.x*v0.x + v0.y*v0.y + v0.z*v0.z + v0.w*v0.w
            + v1.x*v1.x + v1.y*v1.y + v1.z*v1.z + v1.w*v1.w;
#pragma unroll
  for (int o = 32; o > 0; o >>= 1) {
    sum += __shfl_down(sum, o);
    sq  += __shfl_down(sq, o);
  }
  __shared__ float red[8];
  const int wv = t >> 6, l = t & 63;
  if (l == 0) { red[wv] = sum; red[4 + wv] = sq; }
  __syncthreads();
  sum = red[0] + red[1] + red[2] + red[3];
  sq  = red[4] + red[5] + red[6] + red[7];
  const float mu = sum * (1.0f / 2048.0f);
  const float var = sq * (1.0f / 2048.0f) - mu * mu;
  const float rs = rsqrtf(var + 1e-5f);

  float4 g0 = *(const float4*)(gw + t * 8);
  float4 g1 = *(const float4*)(gw + t * 8 + 4);
  float4 b0 = *(const float4*)(bw + t * 8);
  float4 b1 = *(const float4*)(bw + t * 8 + 4);
  u16x8 r;
  r[0] = f2bf((v0.x - mu) * rs * g0.x + b0.x);
  r[1] = f2bf((v0.y - mu) * rs * g0.y + b0.y);
  r[2] = f2bf((v0.z - mu) * rs * g0.z + b0.z);
  r[3] = f2bf((v0.w - mu) * rs * g0.w + b0.w);
  r[4] = f2bf((v1.x - mu) * rs * g1.x + b1.x);
  r[5] = f2bf((v1.y - mu) * rs * g1.y + b1.y);
  r[6] = f2bf((v1.z - mu) * rs * g1.z + b1.z);
  r[7] = f2bf((v1.w - mu) * rs * g1.w + b1.w);
  *(u16x8*)(orow + t * 8) = r;
}

// ---------------- GEMM: C[M,2048] = A[M,2048] @ W[2048,2048]^T, bf16 in ----------------
// mode 0: head-split bf16  dst[((b*16+h)*S_out + s)*128 + d]
// mode 1: V-transpose bf16 dst[((b*16+h)*128 + d)*S_out + s]
// mode 2: linear FLOAT32   dstf[row*2048 + col]   (d_out is f32!)
__global__ __launch_bounds__(256) void gemm_bt_kernel(
    const unsigned short* __restrict__ A, const unsigned short* __restrict__ W,
    void* __restrict__ dst, int mode, int rows_per_b, int S_out) {
  __shared__ unsigned short As[128][32];
  __shared__ unsigned short Bs[128][32];
  const int tid = threadIdx.x;
  const int w = tid >> 6, l = tid & 63;
  const int bm = blockIdx.x >> 4;   // N/128 = 16 column-tiles
  const int bn = blockIdx.x & 15;
  const int wr = w >> 1, wc = w & 1;
  const int fr = l & 15, fg = l >> 4;
  const int lrow = l >> 2, lcol = (l & 3) * 8;

  f32x4 acc[4][4] = {};
  const unsigned short* ga = A + (size_t)(bm * 128 + w * 32 + lrow) * 2048 + lcol;
  const unsigned short* gb = W + (size_t)(bn * 128 + w * 32 + lrow) * 2048 + lcol;

  for (int k0 = 0; k0 < 2048; k0 += 32) {
    gload_lds16(ga + k0,             &As[w * 32][0]);
    gload_lds16(ga + k0 + 16 * 2048, &As[w * 32 + 16][0]);
    gload_lds16(gb + k0,             &Bs[w * 32][0]);
    gload_lds16(gb + k0 + 16 * 2048, &Bs[w * 32 + 16][0]);
    __syncthreads();
    bf16x8 af[4], bfr[4];
#pragma unroll
    for (int mi = 0; mi < 4; ++mi)
      af[mi] = *(const bf16x8*)&As[wr * 64 + mi * 16 + fr][fg * 8];
#pragma unroll
    for (int ni = 0; ni < 4; ++ni)
      bfr[ni] = *(const bf16x8*)&Bs[wc * 64 + ni * 16 + fr][fg * 8];
#pragma unroll
    for (int mi = 0; mi < 4; ++mi)
#pragma unroll
      for (int ni = 0; ni < 4; ++ni)
        acc[mi][ni] = MFMA16(af[mi], bfr[ni], acc[mi][ni]);
    __syncthreads();
  }

#pragma unroll
  for (int mi = 0; mi < 4; ++mi) {
#pragma unroll
    for (int r = 0; r < 4; ++r) {
      int row = bm * 128 + wr * 64 + mi * 16 + fg * 4 + r;
      int b = 0, s = row;
      if (mode != 2) { b = row / rows_per_b; s = row - b * rows_per_b; }
#pragma unroll
      for (int ni = 0; ni < 4; ++ni) {
        int col = bn * 128 + wc * 64 + ni * 16 + fr;
        float v = acc[mi][ni][r];
        if (mode == 2) {
          ((float*)dst)[(size_t)row * 2048 + col] = v;   // d_out is FLOAT32
        } else {
          int h = col >> 7, d = col & 127;
          size_t idx;
          if (mode == 0) idx = ((size_t)(b * NH + h) * S_out + s) * 128 + d;
          else           idx = ((size_t)(b * NH + h) * 128 + d) * (size_t)S_out + s;
          ((unsigned short*)dst)[idx] = f2bf(v);
        }
      }
    }
  }
}

// ---------------- flash attention ----------------
// grid: (Sq/64, H, B); block 256 (4 waves, 16 q-rows each); KV tile = 32
__global__ __launch_bounds__(256) void attn_kernel(
    const unsigned short* __restrict__ Qh, const unsigned short* __restrict__ Kh,
    const unsigned short* __restrict__ Vt, unsigned short* __restrict__ AO, int Sq) {
  __shared__ unsigned short Ks[32][136];   // pad: stride 272B
  __shared__ unsigned short Vs[128][40];   // Vt tile [d][k], stride 80B
  __shared__ unsigned short Ps[4][16][40]; // per-wave P bounce

  const int qt = blockIdx.x, h = blockIdx.y, b = blockIdx.z;
  const int tid = threadIdx.x;
  const int w = tid >> 6, l = tid & 63;
  const int fr = l & 15, fg = l >> 4;
  const size_t bh = (size_t)(b * NH + h);

  // Q fragments stay in registers for the whole KV loop
  const unsigned short* Qbase = Qh + (bh * Sq + (size_t)qt * 64 + w * 16) * HD;
  bf16x8 qf[4];
#pragma unroll
  for (int c = 0; c < 4; ++c)
    qf[c] = *(const bf16x8*)(Qbase + fr * HD + c * 32 + fg * 8);

  f32x4 o[8] = {};
  float m[4], lsum[4];
#pragma unroll
  for (int r = 0; r < 4; ++r) { m[r] = -1e30f; lsum[r] = 0.f; }

  const unsigned short* Kb = Kh + bh * SKV * HD;
  const unsigned short* Vb = Vt + bh * HD * SKV;

  // staging maps: each thread covers 16 contiguous elements (2x bf16x8)
  const int kr = tid >> 3, kc = (tid & 7) * 16;  // K tile 32x128: 8 thr/row
  const int vr = tid >> 1, vc = (tid & 1) * 16;  // V tile 128x32: 2 thr/row

  for (int kt = 0; kt < SKV / 32; ++kt) {
    __syncthreads();
    {
      const unsigned short* gk = Kb + (size_t)(kt * 32 + kr) * HD + kc;
      *(bf16x8*)&Ks[kr][kc]     = *(const bf16x8*)gk;
      *(bf16x8*)&Ks[kr][kc + 8] = *(const bf16x8*)(gk + 8);
      const unsigned short* gv = Vb + (size_t)vr * SKV + kt * 32 + vc;
      *(bf16x8*)&Vs[vr][vc]     = *(const bf16x8*)gv;
      *(bf16x8*)&Vs[vr][vc + 8] = *(const bf16x8*)(gv + 8);
    }
    __syncthreads();

    // S = Q @ K^T  (two 16-col halves)
    f32x4 s0 = {}, s1 = {};
#pragma unroll
    for (int c = 0; c < 4; ++c) {
      bf16x8 k0 = *(const bf16x8*)&Ks[fr][c * 32 + fg * 8];
      bf16x8 k1 = *(const bf16x8*)&Ks[fr + 16][c * 32 + fg * 8];
      s0 = MFMA16(qf[c], k0, s0);
      s1 = MFMA16(qf[c], k1, s1);
    }

    // online softmax over this 32-wide tile; rows live in 16-lane groups
    float alpha[4];
#pragma unroll
    for (int r = 0; r < 4; ++r) {
      float tm = fmaxf(s0[r], s1[r]);
      tm = fmaxf(tm, __shfl_xor(tm, 1));
      tm = fmaxf(tm, __shfl_xor(tm, 2));
      tm = fmaxf(tm, __shfl_xor(tm, 4));
      tm = fmaxf(tm, __shfl_xor(tm, 8));
      float mn = fmaxf(m[r], tm);
      float al = __expf(m[r] - mn);
      float p0 = __expf(s0[r] - mn);
      float p1 = __expf(s1[r] - mn);
      float ts = p0 + p1;
      ts += __shfl_xor(ts, 1);
      ts += __shfl_xor(ts, 2);
      ts += __shfl_xor(ts, 4);
      ts += __shfl_xor(ts, 8);
      lsum[r] = lsum[r] * al + ts;
      m[r] = mn;
      alpha[r] = al;
      unsigned short* pr = &Ps[w][fg * 4 + r][0];
      pr[fr]      = f2bf(p0);
      pr[fr + 16] = f2bf(p1);
    }
#pragma unroll
    for (int nt = 0; nt < 8; ++nt) {
      f32x4 t = o[nt];
      t[0] *= alpha[0]; t[1] *= alpha[1]; t[2] *= alpha[2]; t[3] *= alpha[3];
      o[nt] = t;
    }

    // order the cross-lane Ps writes against the pa read below
    __syncthreads();

    // O += P @ V   (P re-read in A-fragment layout; V^T rows are B-operand)
    bf16x8 pa = *(const bf16x8*)&Ps[w][fr][fg * 8];
#pragma unroll
    for (int nt = 0; nt < 8; ++nt) {
      bf16x8 vb = *(const bf16x8*)&Vs[fr + nt * 16][fg * 8];
      o[nt] = MFMA16(pa, vb, o[nt]);
    }
  }

  // epilogue: divide by lsum, scatter bf16 into AO [B*Sq, 2048]
  unsigned short* Orow = AO + ((size_t)b * Sq + (size_t)qt * 64 + w * 16) * D_MODEL + h * HD;
#pragma unroll
  for (int r = 0; r < 4; ++r) {
    float inv = 1.0f / lsum[r];
    int q = fg * 4 + r;
#pragma unroll
    for (int nt = 0; nt < 8; ++nt)
      Orow[(size_t)q * D_MODEL + nt * 16 + fr] = f2bf(o[nt][r] * inv);
  }
}

// ---------------- host launch ----------------
extern "C" void kernel_launch(void* const* d_in, const int* in_sizes, int n_in,
                              void* d_out, int out_size, void* d_ws, size_t ws_size,
                              hipStream_t stream) {
  const float* q_text  = (const float*)d_in[0];
  const float* q_image = (const float*)d_in[1];
  const float* k_text  = (const float*)d_in[2];
  const float* k_image = (const float*)d_in[3];
  const float* Wq = (const float*)d_in[4];
  const float* Wk = (const float*)d_in[5];
  const float* Wv = (const float*)d_in[6];
  const float* Wo = (const float*)d_in[7];
  const float* ln_tg = (const float*)d_in[8];
  const float* ln_tb = (const float*)d_in[9];
  const float* ln_ig = (const float*)d_in[10];
  const float* ln_ib = (const float*)d_in[11];

  // workspace layout (bf16 elements)
  unsigned short* wq  = (unsigned short*)d_ws;
  unsigned short* wk  = wq  + 4194304;
  unsigned short* wv  = wk  + 4194304;
  unsigned short* wo  = wv  + 4194304;
  unsigned short* xqt = wo  + 4194304;   // LN'd q_text  [2,2048,2048]; later AO_text
  unsigned short* xqi = xqt + 8388608;   // LN'd q_image [2,1024,2048]; later AO_image
  unsigned short* xk  = xqi + 4194304;   // LN'd concat k [2,3072,2048]
  unsigned short* qht = xk  + 12582912;  // [2,16,2048,128]
  unsigned short* qhi = qht + 8388608;   // [2,16,1024,128]
  unsigned short* kh  = qhi + 4194304;   // [2,16,3072,128]
  unsigned short* vt  = kh  + 12582912;  // [2,16,128,3072]
  const size_t needed = (size_t)(vt + 12582912 - wq) * 2;
  if (ws_size < needed) return;

  // weights -> bf16 (fold softmax scale into Wq)
  cvt_w_kernel<<<2048, 256, 0, stream>>>(Wq, wq, QK_SCALE, 524288);
  cvt_w_kernel<<<2048, 256, 0, stream>>>(Wk, wk, 1.0f, 524288);
  cvt_w_kernel<<<2048, 256, 0, stream>>>(Wv, wv, 1.0f, 524288);
  cvt_w_kernel<<<2048, 256, 0, stream>>>(Wo, wo, 1.0f, 524288);

  // LayerNorms
  ln_kernel<<<4096, 256, 0, stream>>>(q_text,  ln_tg, ln_tb, xqt, 2048, 2048, 0);
  ln_kernel<<<2048, 256, 0, stream>>>(q_image, ln_ig, ln_ib, xqi, 1024, 1024, 0);
  ln_kernel<<<4096, 256, 0, stream>>>(k_text,  ln_tg, ln_tb, xk, 2048, 3072, 0);
  ln_kernel<<<2048, 256, 0, stream>>>(k_image, ln_ig, ln_ib, xk, 1024, 3072, 2048);

  // projections
  gemm_bt_kernel<<<512, 256, 0, stream>>>(xqt, wq, qht, 0, 2048, 2048);
  gemm_bt_kernel<<<256, 256, 0, stream>>>(xqi, wq, qhi, 0, 1024, 1024);
  gemm_bt_kernel<<<768, 256, 0, stream>>>(xk,  wk, kh,  0, 3072, 3072);
  gemm_bt_kernel<<<768, 256, 0, stream>>>(xk,  wv, vt,  1, 3072, 3072);

  // attention (text and image share K/V)
  attn_kernel<<<dim3(32, 16, 2), 256, 0, stream>>>(qht, kh, vt, xqt, 2048);
  attn_kernel<<<dim3(16, 16, 2), 256, 0, stream>>>(qhi, kh, vt, xqi, 1024);

  // output projection straight into FLOAT32 d_out (text rows, then image rows)
  float* out = (float*)d_out;
  gemm_bt_kernel<<<512, 256, 0, stream>>>(xqt, wo, out, 2, 0, 0);
  gemm_bt_kernel<<<256, 256, 0, stream>>>(xqi, wo, out + 8388608, 2, 0, 0);
}

// Round 5
// 844.640 us; speedup vs baseline: 1.2508x; 1.2508x over previous
//
#include <hip/hip_runtime.h>

// ---------------- types / helpers ----------------
typedef __attribute__((ext_vector_type(8))) short bf16x8;   // 8 bf16 (4 VGPRs)
typedef __attribute__((ext_vector_type(4))) float f32x4;    // MFMA accum
typedef __attribute__((ext_vector_type(8))) unsigned short u16x8;

#define D_MODEL 2048
#define NH 16
#define HD 128
#define SKV 3072
#define QK_SCALE 0.08838834764831845f  // 128^-0.5

__device__ __forceinline__ unsigned short f2bf(float f) {
  unsigned int u = __float_as_uint(f);
  u += 0x7fffu + ((u >> 16) & 1u);     // RNE, finite inputs only
  return (unsigned short)(u >> 16);
}

typedef __attribute__((address_space(1))) void as1_void;
typedef __attribute__((address_space(3))) void as3_void;
__device__ __forceinline__ void gload_lds16(const void* g, void* l) {
  __builtin_amdgcn_global_load_lds((as1_void*)g, (as3_void*)l, 16, 0, 0);
}

#define MFMA16(a, b, c) __builtin_amdgcn_mfma_f32_16x16x32_bf16((a), (b), (c), 0, 0, 0)

// ---------------- weight convert (optionally scaled) ----------------
__global__ __launch_bounds__(256) void cvt_w_kernel(
    const float* __restrict__ src, unsigned short* __restrict__ dst,
    float scale, int n8) {
  int i = blockIdx.x * 256 + threadIdx.x;
  if (i >= n8) return;
  const float4* s = (const float4*)src + (size_t)i * 2;
  float4 a = s[0], b = s[1];
  u16x8 r;
  r[0] = f2bf(a.x * scale); r[1] = f2bf(a.y * scale);
  r[2] = f2bf(a.z * scale); r[3] = f2bf(a.w * scale);
  r[4] = f2bf(b.x * scale); r[5] = f2bf(b.y * scale);
  r[6] = f2bf(b.z * scale); r[7] = f2bf(b.w * scale);
  *((u16x8*)dst + i) = r;
}

// ---------------- LayerNorm -> bf16 (with row remap for K concat) ----------------
__global__ __launch_bounds__(256) void ln_kernel(
    const float* __restrict__ x, const float* __restrict__ gw,
    const float* __restrict__ bw, unsigned short* __restrict__ out,
    int spb, int orpb, int obase) {
  const int row = blockIdx.x;
  const int t = threadIdx.x;
  const int b = row / spb, s = row - b * spb;
  const float* xr = x + (size_t)row * D_MODEL;
  unsigned short* orow = out + ((size_t)b * orpb + obase + s) * D_MODEL;

  float4 v0 = *(const float4*)(xr + t * 8);
  float4 v1 = *(const float4*)(xr + t * 8 + 4);
  float sum = v0.x + v0.y + v0.z + v0.w + v1.x + v1.y + v1.z + v1.w;
  float sq  = v0.x*v0.x + v0.y*v0.y + v0.z*v0.z + v0.w*v0.w
            + v1.x*v1.x + v1.y*v1.y + v1.z*v1.z + v1.w*v1.w;
#pragma unroll
  for (int o = 32; o > 0; o >>= 1) {
    sum += __shfl_down(sum, o);
    sq  += __shfl_down(sq, o);
  }
  __shared__ float red[8];
  const int wv = t >> 6, l = t & 63;
  if (l == 0) { red[wv] = sum; red[4 + wv] = sq; }
  __syncthreads();
  sum = red[0] + red[1] + red[2] + red[3];
  sq  = red[4] + red[5] + red[6] + red[7];
  const float mu = sum * (1.0f / 2048.0f);
  const float var = sq * (1.0f / 2048.0f) - mu * mu;
  const float rs = rsqrtf(var + 1e-5f);

  float4 g0 = *(const float4*)(gw + t * 8);
  float4 g1 = *(const float4*)(gw + t * 8 + 4);
  float4 b0 = *(const float4*)(bw + t * 8);
  float4 b1 = *(const float4*)(bw + t * 8 + 4);
  u16x8 r;
  r[0] = f2bf((v0.x - mu) * rs * g0.x + b0.x);
  r[1] = f2bf((v0.y - mu) * rs * g0.y + b0.y);
  r[2] = f2bf((v0.z - mu) * rs * g0.z + b0.z);
  r[3] = f2bf((v0.w - mu) * rs * g0.w + b0.w);
  r[4] = f2bf((v1.x - mu) * rs * g1.x + b1.x);
  r[5] = f2bf((v1.y - mu) * rs * g1.y + b1.y);
  r[6] = f2bf((v1.z - mu) * rs * g1.z + b1.z);
  r[7] = f2bf((v1.w - mu) * rs * g1.w + b1.w);
  *(u16x8*)(orow + t * 8) = r;
}

// ---------------- GEMM: C[M,2048] = A[M,2048] @ W[2048,2048]^T, bf16 in ----------------
// mode 0: head-split bf16           dst[(bh*S_out + s)*128 + d]           (Q)
// mode 3: head-split bf16 SWIZZLED  d ^= (s&7)<<3                          (K)
// mode 1: V-transpose bf16 SWIZZLED dst[(bh*128 + d)*S_out + s_swz]        (V)
// mode 2: linear FLOAT32            dstf[row*2048 + col]                   (out)
__global__ __launch_bounds__(256) void gemm_bt_kernel(
    const unsigned short* __restrict__ A, const unsigned short* __restrict__ W,
    void* __restrict__ dst, int mode, int rows_per_b, int S_out) {
  __shared__ unsigned short As[128][32];
  __shared__ unsigned short Bs[128][32];
  const int tid = threadIdx.x;
  const int w = tid >> 6, l = tid & 63;
  const int bm = blockIdx.x >> 4;   // N/128 = 16 column-tiles
  const int bn = blockIdx.x & 15;
  const int wr = w >> 1, wc = w & 1;
  const int fr = l & 15, fg = l >> 4;
  const int lrow = l >> 2, lcol = (l & 3) * 8;

  f32x4 acc[4][4] = {};
  const unsigned short* ga = A + (size_t)(bm * 128 + w * 32 + lrow) * 2048 + lcol;
  const unsigned short* gb = W + (size_t)(bn * 128 + w * 32 + lrow) * 2048 + lcol;

  for (int k0 = 0; k0 < 2048; k0 += 32) {
    gload_lds16(ga + k0,             &As[w * 32][0]);
    gload_lds16(ga + k0 + 16 * 2048, &As[w * 32 + 16][0]);
    gload_lds16(gb + k0,             &Bs[w * 32][0]);
    gload_lds16(gb + k0 + 16 * 2048, &Bs[w * 32 + 16][0]);
    __syncthreads();
    bf16x8 af[4], bfr[4];
#pragma unroll
    for (int mi = 0; mi < 4; ++mi)
      af[mi] = *(const bf16x8*)&As[wr * 64 + mi * 16 + fr][fg * 8];
#pragma unroll
    for (int ni = 0; ni < 4; ++ni)
      bfr[ni] = *(const bf16x8*)&Bs[wc * 64 + ni * 16 + fr][fg * 8];
#pragma unroll
    for (int mi = 0; mi < 4; ++mi)
#pragma unroll
      for (int ni = 0; ni < 4; ++ni)
        acc[mi][ni] = MFMA16(af[mi], bfr[ni], acc[mi][ni]);
    __syncthreads();
  }

#pragma unroll
  for (int mi = 0; mi < 4; ++mi) {
#pragma unroll
    for (int r = 0; r < 4; ++r) {
      int row = bm * 128 + wr * 64 + mi * 16 + fg * 4 + r;
      int b = 0, s = row;
      if (mode != 2) { b = row / rows_per_b; s = row - b * rows_per_b; }
#pragma unroll
      for (int ni = 0; ni < 4; ++ni) {
        int col = bn * 128 + wc * 64 + ni * 16 + fr;
        float v = acc[mi][ni][r];
        if (mode == 2) {
          ((float*)dst)[(size_t)row * 2048 + col] = v;   // d_out is FLOAT32
        } else {
          int hh = col >> 7, d = col & 127;
          size_t bh = (size_t)(b * NH + hh);
          size_t idx;
          if (mode == 0)      idx = (bh * S_out + s) * 128 + d;
          else if (mode == 3) idx = (bh * S_out + s) * 128 + (d ^ ((s & 7) << 3));
          else {
            int ssw = (s & ~63) | ((s & 63) ^ ((d & 7) << 3));
            idx = (bh * 128 + d) * (size_t)S_out + ssw;
          }
          ((unsigned short*)dst)[idx] = f2bf(v);
        }
      }
    }
  }
}

// ---------------- flash attention ----------------
// grid: (Sq/128, H, B); block 256 = 4 waves x 32 q-rows; KV tile = 64
// Kh is d-swizzled (d ^= (s&7)<<3), Vt is s-swizzled (sc ^= (d&7)<<3) by producers,
// so linear global_load_lds staging + XOR'd ds_read_b128 is conflict-ideal.
__global__ __launch_bounds__(256, 2) void attn_kernel(
    const unsigned short* __restrict__ Qh, const unsigned short* __restrict__ Kh,
    const unsigned short* __restrict__ Vt, unsigned short* __restrict__ AO, int Sq) {
  __shared__ unsigned short Ks[64 * 128];   // [k][d'], 16 KB
  __shared__ unsigned short Vs[128 * 64];   // [d][k'], 16 KB
  __shared__ unsigned short Ps[4][32 * 64]; // per-wave [q][k'], 16 KB

  const int qt = blockIdx.x, h = blockIdx.y, b = blockIdx.z;
  const int tid = threadIdx.x;
  const int w = tid >> 6, l = tid & 63;
  const int fr = l & 15, fg = l >> 4;
  const size_t bh = (size_t)(b * NH + h);

  // Q fragments (2 halves x 4 k-chunks) stay in registers
  const unsigned short* Qbase = Qh + (bh * Sq + (size_t)qt * 128 + w * 32) * HD;
  bf16x8 qf[2][4];
#pragma unroll
  for (int h2 = 0; h2 < 2; ++h2)
#pragma unroll
    for (int c = 0; c < 4; ++c)
      qf[h2][c] = *(const bf16x8*)(Qbase + (h2 * 16 + fr) * HD + c * 32 + fg * 8);

  f32x4 o[2][8] = {};
  float m[2][4], lsum[2][4];
#pragma unroll
  for (int h2 = 0; h2 < 2; ++h2)
#pragma unroll
    for (int r = 0; r < 4; ++r) { m[h2][r] = -1e30f; lsum[h2][r] = 0.f; }

  const unsigned short* Kb = Kh + bh * (size_t)SKV * HD;
  const unsigned short* Vb = Vt + bh * (size_t)HD * SKV;

  const int krow = l >> 4, kcol = (l & 15) * 8;  // K chunk: 4 rows x 128
  const int vrow = l >> 3, vcol = (l & 7) * 8;   // V chunk: 8 rows x 64
  const int sw = (fr & 7) << 3;
  unsigned short* Pw = Ps[w];

  for (int kt = 0; kt < SKV / 64; ++kt) {
    // ---- stage K (64x128) and V (128x64) via global_load_lds, 1KB chunks ----
#pragma unroll
    for (int i = 0; i < 4; ++i) {
      const int ci = w * 4 + i;
      gload_lds16(Kb + (size_t)(kt * 64 + ci * 4 + krow) * HD + kcol, &Ks[ci * 512]);
      gload_lds16(Vb + (size_t)(ci * 8 + vrow) * SKV + kt * 64 + vcol, &Vs[ci * 512]);
    }
    __syncthreads();   // drains vmcnt for the gload_lds

    // ---- S = Q @ K^T : 16x64 per half ----
    f32x4 s[2][4] = {};
#pragma unroll
    for (int j = 0; j < 4; ++j) {
      const int krb = (j * 16 + fr) * 128;
#pragma unroll
      for (int c = 0; c < 4; ++c) {
        bf16x8 kf = *(const bf16x8*)&Ks[krb + ((c * 32 + fg * 8) ^ sw)];
        s[0][j] = MFMA16(qf[0][c], kf, s[0][j]);
        s[1][j] = MFMA16(qf[1][c], kf, s[1][j]);
      }
    }

    // ---- online softmax over 64 cols; rows live in 16-lane groups ----
#pragma unroll
    for (int h2 = 0; h2 < 2; ++h2) {
      float alpha[4];
#pragma unroll
      for (int r = 0; r < 4; ++r) {
        float tm = fmaxf(fmaxf(s[h2][0][r], s[h2][1][r]),
                         fmaxf(s[h2][2][r], s[h2][3][r]));
        tm = fmaxf(tm, __shfl_xor(tm, 1));
        tm = fmaxf(tm, __shfl_xor(tm, 2));
        tm = fmaxf(tm, __shfl_xor(tm, 4));
        tm = fmaxf(tm, __shfl_xor(tm, 8));
        float mn = fmaxf(m[h2][r], tm);
        float al = __expf(m[h2][r] - mn);
        float p0 = __expf(s[h2][0][r] - mn);
        float p1 = __expf(s[h2][1][r] - mn);
        float p2 = __expf(s[h2][2][r] - mn);
        float p3 = __expf(s[h2][3][r] - mn);
        float ts = p0 + p1 + p2 + p3;
        ts += __shfl_xor(ts, 1);
        ts += __shfl_xor(ts, 2);
        ts += __shfl_xor(ts, 4);
        ts += __shfl_xor(ts, 8);
        lsum[h2][r] = lsum[h2][r] * al + ts;
        m[h2][r] = mn;
        alpha[r] = al;
        const int row = h2 * 16 + fg * 4 + r;
        unsigned short* pr = &Pw[row * 64];
        const int rs8 = (row & 7) << 3;
        pr[fr ^ rs8]        = f2bf(p0);
        pr[(16 + fr) ^ rs8] = f2bf(p1);
        pr[(32 + fr) ^ rs8] = f2bf(p2);
        pr[(48 + fr) ^ rs8] = f2bf(p3);
      }
#pragma unroll
      for (int nt = 0; nt < 8; ++nt) {
        f32x4 t = o[h2][nt];
        t[0] *= alpha[0]; t[1] *= alpha[1]; t[2] *= alpha[2]; t[3] *= alpha[3];
        o[h2][nt] = t;
      }
    }

    // order per-wave Ps writes (cross-lane) against the A-frag reads below
    asm volatile("s_waitcnt lgkmcnt(0)" ::: "memory");
    __builtin_amdgcn_sched_barrier(0);

    // ---- O += P @ V ----
    bf16x8 pa[2][2];
#pragma unroll
    for (int h2 = 0; h2 < 2; ++h2)
#pragma unroll
      for (int kc = 0; kc < 2; ++kc)
        pa[h2][kc] = *(const bf16x8*)&Pw[(h2 * 16 + fr) * 64 + ((kc * 32 + fg * 8) ^ sw)];
#pragma unroll
    for (int nt = 0; nt < 8; ++nt) {
      const int vrb = (nt * 16 + fr) * 64;
#pragma unroll
      for (int kc = 0; kc < 2; ++kc) {
        bf16x8 vf = *(const bf16x8*)&Vs[vrb + ((kc * 32 + fg * 8) ^ sw)];
        o[0][nt] = MFMA16(pa[0][kc], vf, o[0][nt]);
        o[1][nt] = MFMA16(pa[1][kc], vf, o[1][nt]);
      }
    }
    __syncthreads();   // all waves done reading Ks/Vs before next stage
  }

  // ---- epilogue: divide by lsum, scatter bf16 into AO [B*Sq, 2048] ----
#pragma unroll
  for (int h2 = 0; h2 < 2; ++h2) {
    unsigned short* Orow = AO + ((size_t)b * Sq + (size_t)qt * 128 + w * 32 + h2 * 16) * D_MODEL + h * HD;
#pragma unroll
    for (int r = 0; r < 4; ++r) {
      float inv = 1.0f / lsum[h2][r];
      int q = fg * 4 + r;
#pragma unroll
      for (int nt = 0; nt < 8; ++nt)
        Orow[(size_t)q * D_MODEL + nt * 16 + fr] = f2bf(o[h2][nt][r] * inv);
    }
  }
}

// ---------------- host launch ----------------
extern "C" void kernel_launch(void* const* d_in, const int* in_sizes, int n_in,
                              void* d_out, int out_size, void* d_ws, size_t ws_size,
                              hipStream_t stream) {
  const float* q_text  = (const float*)d_in[0];
  const float* q_image = (const float*)d_in[1];
  const float* k_text  = (const float*)d_in[2];
  const float* k_image = (const float*)d_in[3];
  const float* Wq = (const float*)d_in[4];
  const float* Wk = (const float*)d_in[5];
  const float* Wv = (const float*)d_in[6];
  const float* Wo = (const float*)d_in[7];
  const float* ln_tg = (const float*)d_in[8];
  const float* ln_tb = (const float*)d_in[9];
  const float* ln_ig = (const float*)d_in[10];
  const float* ln_ib = (const float*)d_in[11];

  // workspace layout (bf16 elements)
  unsigned short* wq  = (unsigned short*)d_ws;
  unsigned short* wk  = wq  + 4194304;
  unsigned short* wv  = wk  + 4194304;
  unsigned short* wo  = wv  + 4194304;
  unsigned short* xqt = wo  + 4194304;   // LN'd q_text  [2,2048,2048]; later AO_text
  unsigned short* xqi = xqt + 8388608;   // LN'd q_image [2,1024,2048]; later AO_image
  unsigned short* xk  = xqi + 4194304;   // LN'd concat k [2,3072,2048]
  unsigned short* qht = xk  + 12582912;  // [2,16,2048,128]
  unsigned short* qhi = qht + 8388608;   // [2,16,1024,128]
  unsigned short* kh  = qhi + 4194304;   // [2,16,3072,128] (d-swizzled)
  unsigned short* vt  = kh  + 12582912;  // [2,16,128,3072] (s-swizzled)
  const size_t needed = (size_t)(vt + 12582912 - wq) * 2;
  if (ws_size < needed) return;

  // weights -> bf16 (fold softmax scale into Wq)
  cvt_w_kernel<<<2048, 256, 0, stream>>>(Wq, wq, QK_SCALE, 524288);
  cvt_w_kernel<<<2048, 256, 0, stream>>>(Wk, wk, 1.0f, 524288);
  cvt_w_kernel<<<2048, 256, 0, stream>>>(Wv, wv, 1.0f, 524288);
  cvt_w_kernel<<<2048, 256, 0, stream>>>(Wo, wo, 1.0f, 524288);

  // LayerNorms
  ln_kernel<<<4096, 256, 0, stream>>>(q_text,  ln_tg, ln_tb, xqt, 2048, 2048, 0);
  ln_kernel<<<2048, 256, 0, stream>>>(q_image, ln_ig, ln_ib, xqi, 1024, 1024, 0);
  ln_kernel<<<4096, 256, 0, stream>>>(k_text,  ln_tg, ln_tb, xk, 2048, 3072, 0);
  ln_kernel<<<2048, 256, 0, stream>>>(k_image, ln_ig, ln_ib, xk, 1024, 3072, 2048);

  // projections (Q linear head-split; K d-swizzled; V transposed s-swizzled)
  gemm_bt_kernel<<<512, 256, 0, stream>>>(xqt, wq, qht, 0, 2048, 2048);
  gemm_bt_kernel<<<256, 256, 0, stream>>>(xqi, wq, qhi, 0, 1024, 1024);
  gemm_bt_kernel<<<768, 256, 0, stream>>>(xk,  wk, kh,  3, 3072, 3072);
  gemm_bt_kernel<<<768, 256, 0, stream>>>(xk,  wv, vt,  1, 3072, 3072);

  // attention (text and image share K/V)
  attn_kernel<<<dim3(16, 16, 2), 256, 0, stream>>>(qht, kh, vt, xqt, 2048);
  attn_kernel<<<dim3(8, 16, 2),  256, 0, stream>>>(qhi, kh, vt, xqi, 1024);

  // output projection straight into FLOAT32 d_out (text rows, then image rows)
  float* out = (float*)d_out;
  gemm_bt_kernel<<<512, 256, 0, stream>>>(xqt, wo, out, 2, 0, 0);
  gemm_bt_kernel<<<256, 256, 0, stream>>>(xqi, wo, out + 8388608, 2, 0, 0);
}

// Round 6
// 621.921 us; speedup vs baseline: 1.6987x; 1.3581x over previous
//
#include <hip/hip_runtime.h>

// ---------------- types / helpers ----------------
typedef __attribute__((ext_vector_type(8))) short bf16x8;   // 8 bf16 (4 VGPRs)
typedef __attribute__((ext_vector_type(4))) float f32x4;    // MFMA accum
typedef __attribute__((ext_vector_type(8))) unsigned short u16x8;
typedef __attribute__((ext_vector_type(4))) unsigned short u16x4;

#define D_MODEL 2048
#define NH 16
#define HD 128
#define SKV 3072
#define QK_SCALE 0.08838834764831845f  // 128^-0.5

__device__ __forceinline__ unsigned short f2bf(float f) {
  unsigned int u = __float_as_uint(f);
  u += 0x7fffu + ((u >> 16) & 1u);     // RNE, finite inputs only
  return (unsigned short)(u >> 16);
}

typedef __attribute__((address_space(1))) void as1_void;
typedef __attribute__((address_space(3))) void as3_void;
__device__ __forceinline__ void gload_lds16(const void* g, void* l) {
  __builtin_amdgcn_global_load_lds((as1_void*)g, (as3_void*)l, 16, 0, 0);
}

#define MFMA16(a, b, c) __builtin_amdgcn_mfma_f32_16x16x32_bf16((a), (b), (c), 0, 0, 0)

// ---------------- weight convert: all 4 weights in one dispatch ----------------
__global__ __launch_bounds__(256) void cvt_w_kernel(
    const float* __restrict__ s0, const float* __restrict__ s1,
    const float* __restrict__ s2, const float* __restrict__ s3,
    unsigned short* __restrict__ dstbase) {
  const int y = blockIdx.y;
  const float* src = (y == 0) ? s0 : (y == 1) ? s1 : (y == 2) ? s2 : s3;
  const float scale = (y == 0) ? QK_SCALE : 1.0f;
  unsigned short* dst = dstbase + (size_t)y * 4194304;
  int i = blockIdx.x * 256 + threadIdx.x;
  const float4* s = (const float4*)src + (size_t)i * 2;
  float4 a = s[0], b = s[1];
  u16x8 r;
  r[0] = f2bf(a.x * scale); r[1] = f2bf(a.y * scale);
  r[2] = f2bf(a.z * scale); r[3] = f2bf(a.w * scale);
  r[4] = f2bf(b.x * scale); r[5] = f2bf(b.y * scale);
  r[6] = f2bf(b.z * scale); r[7] = f2bf(b.w * scale);
  *((u16x8*)dst + i) = r;
}

// ---------------- LayerNorm -> bf16 (with row remap for K concat) ----------------
__global__ __launch_bounds__(256) void ln_kernel(
    const float* __restrict__ x, const float* __restrict__ gw,
    const float* __restrict__ bw, unsigned short* __restrict__ out,
    int spb, int orpb, int obase) {
  const int row = blockIdx.x;
  const int t = threadIdx.x;
  const int b = row / spb, s = row - b * spb;
  const float* xr = x + (size_t)row * D_MODEL;
  unsigned short* orow = out + ((size_t)b * orpb + obase + s) * D_MODEL;

  float4 v0 = *(const float4*)(xr + t * 8);
  float4 v1 = *(const float4*)(xr + t * 8 + 4);
  float sum = v0.x + v0.y + v0.z + v0.w + v1.x + v1.y + v1.z + v1.w;
  float sq  = v0.x*v0.x + v0.y*v0.y + v0.z*v0.z + v0.w*v0.w
            + v1.x*v1.x + v1.y*v1.y + v1.z*v1.z + v1.w*v1.w;
#pragma unroll
  for (int o = 32; o > 0; o >>= 1) {
    sum += __shfl_down(sum, o);
    sq  += __shfl_down(sq, o);
  }
  __shared__ float red[8];
  const int wv = t >> 6, l = t & 63;
  if (l == 0) { red[wv] = sum; red[4 + wv] = sq; }
  __syncthreads();
  sum = red[0] + red[1] + red[2] + red[3];
  sq  = red[4] + red[5] + red[6] + red[7];
  const float mu = sum * (1.0f / 2048.0f);
  const float var = sq * (1.0f / 2048.0f) - mu * mu;
  const float rs = rsqrtf(var + 1e-5f);

  float4 g0 = *(const float4*)(gw + t * 8);
  float4 g1 = *(const float4*)(gw + t * 8 + 4);
  float4 b0 = *(const float4*)(bw + t * 8);
  float4 b1 = *(const float4*)(bw + t * 8 + 4);
  u16x8 r;
  r[0] = f2bf((v0.x - mu) * rs * g0.x + b0.x);
  r[1] = f2bf((v0.y - mu) * rs * g0.y + b0.y);
  r[2] = f2bf((v0.z - mu) * rs * g0.z + b0.z);
  r[3] = f2bf((v0.w - mu) * rs * g0.w + b0.w);
  r[4] = f2bf((v1.x - mu) * rs * g1.x + b1.x);
  r[5] = f2bf((v1.y - mu) * rs * g1.y + b1.y);
  r[6] = f2bf((v1.z - mu) * rs * g1.z + b1.z);
  r[7] = f2bf((v1.w - mu) * rs * g1.w + b1.w);
  *(u16x8*)(orow + t * 8) = r;
}

// ---------------- GEMM: C[M,2048] = A[M,2048] @ W[2048,2048]^T, bf16 in ----------------
// mode 0: Q merged   rows<4096 -> dst0 (text, S=2048), else dst1 (image, S=1024)
// mode 2: linear f32 dst0[row*2048+col]  (output projection, M=6144)
// mode 4: KV merged  blockIdx.y==0: K d-swizzled -> dst0 ; y==1: V transposed s-swizzled -> dst1
__global__ __launch_bounds__(256) void gemm_bt_kernel(
    const unsigned short* __restrict__ A,
    const unsigned short* __restrict__ W0, const unsigned short* __restrict__ W1,
    void* __restrict__ dst0, void* __restrict__ dst1, int mode) {
  __shared__ unsigned short As[128][32];
  __shared__ unsigned short Bs[128][32];
  const int tid = threadIdx.x;
  const int w = tid >> 6, l = tid & 63;
  const int bm = blockIdx.x >> 4;   // M/128 tiles
  const int bn = blockIdx.x & 15;   // 2048/128 = 16 col tiles
  const int wr = w >> 1, wc = w & 1;
  const int fr = l & 15, fg = l >> 4;
  const int lrow = l >> 2, lcol = (l & 3) * 8;

  const unsigned short* W = W0;
  int m = mode;
  if (mode == 4) { if (blockIdx.y == 0) m = 3; else { m = 1; W = W1; } }

  f32x4 acc[4][4] = {};
  const unsigned short* ga = A + (size_t)(bm * 128 + w * 32 + lrow) * 2048 + lcol;
  const unsigned short* gb = W + (size_t)(bn * 128 + w * 32 + lrow) * 2048 + lcol;

  for (int k0 = 0; k0 < 2048; k0 += 32) {
    gload_lds16(ga + k0,             &As[w * 32][0]);
    gload_lds16(ga + k0 + 16 * 2048, &As[w * 32 + 16][0]);
    gload_lds16(gb + k0,             &Bs[w * 32][0]);
    gload_lds16(gb + k0 + 16 * 2048, &Bs[w * 32 + 16][0]);
    __syncthreads();
    bf16x8 af[4], bfr[4];
#pragma unroll
    for (int mi = 0; mi < 4; ++mi)
      af[mi] = *(const bf16x8*)&As[wr * 64 + mi * 16 + fr][fg * 8];
#pragma unroll
    for (int ni = 0; ni < 4; ++ni)
      bfr[ni] = *(const bf16x8*)&Bs[wc * 64 + ni * 16 + fr][fg * 8];
#pragma unroll
    for (int mi = 0; mi < 4; ++mi)
#pragma unroll
      for (int ni = 0; ni < 4; ++ni)
        acc[mi][ni] = MFMA16(af[mi], bfr[ni], acc[mi][ni]);
    __syncthreads();
  }

#pragma unroll
  for (int mi = 0; mi < 4; ++mi) {
#pragma unroll
    for (int r = 0; r < 4; ++r) {
      int row = bm * 128 + wr * 64 + mi * 16 + fg * 4 + r;
#pragma unroll
      for (int ni = 0; ni < 4; ++ni) {
        int col = bn * 128 + wc * 64 + ni * 16 + fr;
        float v = acc[mi][ni][r];
        if (m == 2) {
          ((float*)dst0)[(size_t)row * 2048 + col] = v;   // d_out is FLOAT32
        } else if (m == 0) {
          int hh = col >> 7, d = col & 127;
          if (row < 4096) {
            int b = row >> 11, s = row & 2047;
            ((unsigned short*)dst0)[((size_t)(b * NH + hh) * 2048 + s) * 128 + d] = f2bf(v);
          } else {
            int rr = row - 4096, b = rr >> 10, s = rr & 1023;
            ((unsigned short*)dst1)[((size_t)(b * NH + hh) * 1024 + s) * 128 + d] = f2bf(v);
          }
        } else {
          int b = row / 3072, s = row - b * 3072;
          int hh = col >> 7, d = col & 127;
          size_t bh = (size_t)(b * NH + hh);
          if (m == 3) {
            ((unsigned short*)dst0)[(bh * 3072 + s) * 128 + (d ^ ((s & 7) << 3))] = f2bf(v);
          } else {
            int ssw = (s & ~63) | ((s & 63) ^ ((d & 7) << 3));
            ((unsigned short*)dst1)[(bh * 128 + d) * (size_t)3072 + ssw] = f2bf(v);
          }
        }
      }
    }
  }
}

// ---------------- flash attention: text+image merged, swapped-operand ----------------
// grid: 768 blocks (1D). XCD-chunked decode -> (qt24, h, b). qt24<16: text else image.
// 4 waves x 32 q-rows = 128 q/block; KV tile = 64.
// S^T = mfma(K, Q): lane col = q, rows = k -> softmax reduction is (mostly) in-lane.
// O^T = mfma(V^T, P^T): accumulate [d][q], transpose once in epilogue via LDS.
__global__ __launch_bounds__(256, 3) void attn_kernel(
    const unsigned short* __restrict__ Qt, const unsigned short* __restrict__ Qi,
    const unsigned short* __restrict__ Kh, const unsigned short* __restrict__ Vt,
    unsigned short* __restrict__ AOt, unsigned short* __restrict__ AOi) {
  __shared__ unsigned short Sh[24576];   // Ks 8192 | Vs 8192 | Ps 4x2048 (shorts)
  unsigned short* Ks = Sh;
  unsigned short* Vs = Sh + 8192;

  const int lin = blockIdx.x;
  const int w768 = (lin & 7) * 96 + (lin >> 3);    // XCD-chunked (768 % 8 == 0)
  const int qt24 = w768 % 24;
  const int hb   = w768 / 24;
  const int h = hb & 15, b = hb >> 4;
  const bool is_text = qt24 < 16;
  const int qt = is_text ? qt24 : qt24 - 16;
  const int Sq = is_text ? 2048 : 1024;
  const unsigned short* Qh = is_text ? Qt : Qi;
  unsigned short* AO = is_text ? AOt : AOi;

  const int tid = threadIdx.x;
  const int w = tid >> 6, l = tid & 63;
  const int fr = l & 15, fg = l >> 4;
  const size_t bh = (size_t)(b * NH + h);
  unsigned short* Pw = Sh + 16384 + w * 2048;      // per-wave P [32 q][64 k]

  // Q fragments (B-operand: lane fr = q, k-contig d at fg*8) — 2 halves x 4 d-chunks
  const unsigned short* Qbase = Qh + (bh * Sq + (size_t)qt * 128 + w * 32) * HD;
  bf16x8 qf[2][4];
#pragma unroll
  for (int h2 = 0; h2 < 2; ++h2)
#pragma unroll
    for (int c = 0; c < 4; ++c)
      qf[h2][c] = *(const bf16x8*)(Qbase + (h2 * 16 + fr) * HD + c * 32 + fg * 8);

  f32x4 o[2][8] = {};     // O^T: [h2][nt] rows d = nt*16+fg*4+r, col q = fr
  float m[2]    = {-1e30f, -1e30f};
  float lsum[2] = {0.f, 0.f};

  const unsigned short* Kb = Kh + bh * (size_t)SKV * HD;
  const unsigned short* Vb = Vt + bh * (size_t)HD * SKV;

  const int krow = l >> 4, kcol = (l & 15) * 8;  // K chunk: 4 rows x 128
  const int vrow = l >> 3, vcol = (l & 7) * 8;   // V chunk: 8 rows x 64
  const int sw = (fr & 7) << 3;

  for (int kt = 0; kt < SKV / 64; ++kt) {
    // ---- stage K (64x128) and V (128x64) via global_load_lds ----
#pragma unroll
    for (int i = 0; i < 4; ++i) {
      const int ci = w * 4 + i;
      gload_lds16(Kb + (size_t)(kt * 64 + ci * 4 + krow) * HD + kcol, &Ks[ci * 512]);
      gload_lds16(Vb + (size_t)(ci * 8 + vrow) * SKV + kt * 64 + vcol, &Vs[ci * 512]);
    }
    __syncthreads();

    // ---- S^T = K @ Q^T : rows k (j*16+fg*4+r), col q = fr ----
    f32x4 sT[2][4] = {};
#pragma unroll
    for (int j = 0; j < 4; ++j) {
      const int krb = (j * 16 + fr) * 128;
#pragma unroll
      for (int c = 0; c < 4; ++c) {
        bf16x8 kf = *(const bf16x8*)&Ks[krb + ((c * 32 + fg * 8) ^ sw)];
        sT[0][j] = MFMA16(kf, qf[0][c], sT[0][j]);
        sT[1][j] = MFMA16(kf, qf[1][c], sT[1][j]);
      }
    }

    // ---- per-lane softmax (q = fr), defer-max rescale, packed P writes ----
#pragma unroll
    for (int h2 = 0; h2 < 2; ++h2) {
      float tm = sT[h2][0][0];
#pragma unroll
      for (int j = 0; j < 4; ++j)
#pragma unroll
        for (int r = 0; r < 4; ++r) tm = fmaxf(tm, sT[h2][j][r]);
      tm = fmaxf(tm, __shfl_xor(tm, 16));
      tm = fmaxf(tm, __shfl_xor(tm, 32));
      if (__any(tm - m[h2] > 8.0f)) {
        float mn = fmaxf(m[h2], tm);
        float al = __expf(m[h2] - mn);
#pragma unroll
        for (int nt = 0; nt < 8; ++nt) {
          f32x4 t = o[h2][nt];
          t[0] *= al; t[1] *= al; t[2] *= al; t[3] *= al;
          o[h2][nt] = t;
        }
        lsum[h2] *= al;
        m[h2] = mn;
      }
      const float mm = m[h2];
      float ps = 0.f;
      unsigned short* prow = &Pw[(h2 * 16 + fr) * 64];
#pragma unroll
      for (int j = 0; j < 4; ++j) {
        u16x4 pk;
#pragma unroll
        for (int r = 0; r < 4; ++r) {
          float p = __expf(sT[h2][j][r] - mm);
          ps += p;
          pk[r] = f2bf(p);
        }
        *reinterpret_cast<u16x4*>(&prow[(16 * j + fg * 4) ^ sw]) = pk;
      }
      lsum[h2] += ps;
    }

    // order wave-internal cross-lane P writes vs reads (rule 18)
    asm volatile("s_waitcnt lgkmcnt(0)" ::: "memory");
    __builtin_amdgcn_sched_barrier(0);

    // ---- O^T += V^T @ P^T ----
    bf16x8 pb[2][2];
#pragma unroll
    for (int h2 = 0; h2 < 2; ++h2)
#pragma unroll
      for (int kc = 0; kc < 2; ++kc)
        pb[h2][kc] = *(const bf16x8*)&Pw[(h2 * 16 + fr) * 64 + ((kc * 32 + fg * 8) ^ sw)];
#pragma unroll
    for (int nt = 0; nt < 8; ++nt) {
      const int vrb = (nt * 16 + fr) * 64;
#pragma unroll
      for (int kc = 0; kc < 2; ++kc) {
        bf16x8 vf = *(const bf16x8*)&Vs[vrb + ((kc * 32 + fg * 8) ^ sw)];
        o[0][nt] = MFMA16(vf, pb[0][kc], o[0][nt]);
        o[1][nt] = MFMA16(vf, pb[1][kc], o[1][nt]);
      }
    }
    __syncthreads();   // all waves done with Ks/Vs before next stage
  }

  // ---- epilogue: reduce lsum across fg, transpose O^T via LDS, coalesced store ----
  float inv[2];
#pragma unroll
  for (int h2 = 0; h2 < 2; ++h2) {
    float t = lsum[h2];
    t += __shfl_xor(t, 16);
    t += __shfl_xor(t, 32);
    inv[h2] = 1.0f / t;
  }
  unsigned short* Os = &Sh[w * 4096];   // per-wave [32 q][128 d], reuses Ks/Vs space
#pragma unroll
  for (int h2 = 0; h2 < 2; ++h2) {
    unsigned short* orow = &Os[(h2 * 16 + fr) * 128];
#pragma unroll
    for (int nt = 0; nt < 8; ++nt) {
      u16x4 pk;
#pragma unroll
      for (int r = 0; r < 4; ++r) pk[r] = f2bf(o[h2][nt][r] * inv[h2]);
      *reinterpret_cast<u16x4*>(&orow[(nt * 16 + fg * 4) ^ sw]) = pk;
    }
  }
  asm volatile("s_waitcnt lgkmcnt(0)" ::: "memory");
  __builtin_amdgcn_sched_barrier(0);
  const int qr4 = l >> 4;          // 0..3
  const int dc = (l & 15) * 8;
  unsigned short* AObase = AO + ((size_t)b * Sq + (size_t)qt * 128 + w * 32) * D_MODEL + h * HD;
#pragma unroll
  for (int g = 0; g < 8; ++g) {
    const int row = g * 4 + qr4;
    bf16x8 v = *reinterpret_cast<const bf16x8*>(&Os[row * 128 + (dc ^ ((row & 7) << 3))]);
    *reinterpret_cast<bf16x8*>(&AObase[(size_t)row * D_MODEL + dc]) = v;
  }
}

// ---------------- host launch ----------------
extern "C" void kernel_launch(void* const* d_in, const int* in_sizes, int n_in,
                              void* d_out, int out_size, void* d_ws, size_t ws_size,
                              hipStream_t stream) {
  const float* q_text  = (const float*)d_in[0];
  const float* q_image = (const float*)d_in[1];
  const float* k_text  = (const float*)d_in[2];
  const float* k_image = (const float*)d_in[3];
  const float* Wq = (const float*)d_in[4];
  const float* Wk = (const float*)d_in[5];
  const float* Wv = (const float*)d_in[6];
  const float* Wo = (const float*)d_in[7];
  const float* ln_tg = (const float*)d_in[8];
  const float* ln_tb = (const float*)d_in[9];
  const float* ln_ig = (const float*)d_in[10];
  const float* ln_ib = (const float*)d_in[11];

  // workspace layout (bf16 elements); wq..wo contiguous, xqt||xqi contiguous
  unsigned short* wq  = (unsigned short*)d_ws;
  unsigned short* wk  = wq  + 4194304;
  unsigned short* wv  = wk  + 4194304;
  unsigned short* wo  = wv  + 4194304;
  unsigned short* xqt = wo  + 4194304;   // LN'd q_text  [4096,2048]; later AO_text
  unsigned short* xqi = xqt + 8388608;   // LN'd q_image [2048,2048]; later AO_image
  unsigned short* xk  = xqi + 4194304;   // LN'd concat k [2,3072,2048]
  unsigned short* qht = xk  + 12582912;  // [2,16,2048,128]
  unsigned short* qhi = qht + 8388608;   // [2,16,1024,128]
  unsigned short* kh  = qhi + 4194304;   // [2,16,3072,128] (d-swizzled)
  unsigned short* vt  = kh  + 12582912;  // [2,16,128,3072] (s-swizzled)
  const size_t needed = (size_t)(vt + 12582912 - wq) * 2;
  if (ws_size < needed) return;

  // weights -> bf16 (fold softmax scale into Wq), one dispatch
  cvt_w_kernel<<<dim3(2048, 4), 256, 0, stream>>>(Wq, Wk, Wv, Wo, wq);

  // LayerNorms
  ln_kernel<<<4096, 256, 0, stream>>>(q_text,  ln_tg, ln_tb, xqt, 2048, 2048, 0);
  ln_kernel<<<2048, 256, 0, stream>>>(q_image, ln_ig, ln_ib, xqi, 1024, 1024, 0);
  ln_kernel<<<4096, 256, 0, stream>>>(k_text,  ln_tg, ln_tb, xk, 2048, 3072, 0);
  ln_kernel<<<2048, 256, 0, stream>>>(k_image, ln_ig, ln_ib, xk, 1024, 3072, 2048);

  // projections: Q (text+image merged, M=6144), K+V (merged via grid.y)
  gemm_bt_kernel<<<768, 256, 0, stream>>>(xqt, wq, nullptr, qht, qhi, 0);
  gemm_bt_kernel<<<dim3(768, 2), 256, 0, stream>>>(xk, wk, wv, kh, vt, 4);

  // attention: text+image in one dispatch
  attn_kernel<<<768, 256, 0, stream>>>(qht, qhi, kh, vt, xqt, xqi);

  // output projection: M=6144 straight into FLOAT32 d_out (text rows then image rows)
  gemm_bt_kernel<<<768, 256, 0, stream>>>(xqt, wo, nullptr, d_out, nullptr, 2);
}

// Round 7
// 538.556 us; speedup vs baseline: 1.9617x; 1.1548x over previous
//
#include <hip/hip_runtime.h>

// ---------------- types / helpers ----------------
typedef __attribute__((ext_vector_type(8))) short bf16x8;   // 8 bf16 (4 VGPRs)
typedef __attribute__((ext_vector_type(4))) float f32x4;    // MFMA accum
typedef __attribute__((ext_vector_type(8))) unsigned short u16x8;
typedef __attribute__((ext_vector_type(4))) unsigned short u16x4;

#define D_MODEL 2048
#define NH 16
#define HD 128
#define SKV 3072
#define QK_SCALE 0.08838834764831845f  // 128^-0.5

__device__ __forceinline__ unsigned short f2bf(float f) {
  unsigned int u = __float_as_uint(f);
  u += 0x7fffu + ((u >> 16) & 1u);     // RNE, finite inputs only
  return (unsigned short)(u >> 16);
}

typedef __attribute__((address_space(1))) void as1_void;
typedef __attribute__((address_space(3))) void as3_void;
__device__ __forceinline__ void gload_lds16(const void* g, void* l) {
  __builtin_amdgcn_global_load_lds((as1_void*)g, (as3_void*)l, 16, 0, 0);
}

#define MFMA16(a, b, c) __builtin_amdgcn_mfma_f32_16x16x32_bf16((a), (b), (c), 0, 0, 0)

// ---------------- weight convert: all 4 weights in one dispatch ----------------
__global__ __launch_bounds__(256) void cvt_w_kernel(
    const float* __restrict__ s0, const float* __restrict__ s1,
    const float* __restrict__ s2, const float* __restrict__ s3,
    unsigned short* __restrict__ dstbase) {
  const int y = blockIdx.y;
  const float* src = (y == 0) ? s0 : (y == 1) ? s1 : (y == 2) ? s2 : s3;
  const float scale = (y == 0) ? QK_SCALE : 1.0f;
  unsigned short* dst = dstbase + (size_t)y * 4194304;
  int i = blockIdx.x * 256 + threadIdx.x;
  const float4* s = (const float4*)src + (size_t)i * 2;
  float4 a = s[0], b = s[1];
  u16x8 r;
  r[0] = f2bf(a.x * scale); r[1] = f2bf(a.y * scale);
  r[2] = f2bf(a.z * scale); r[3] = f2bf(a.w * scale);
  r[4] = f2bf(b.x * scale); r[5] = f2bf(b.y * scale);
  r[6] = f2bf(b.z * scale); r[7] = f2bf(b.w * scale);
  *((u16x8*)dst + i) = r;
}

// ---------------- LayerNorm -> bf16 (with row remap for K concat) ----------------
__global__ __launch_bounds__(256) void ln_kernel(
    const float* __restrict__ x, const float* __restrict__ gw,
    const float* __restrict__ bw, unsigned short* __restrict__ out,
    int spb, int orpb, int obase) {
  const int row = blockIdx.x;
  const int t = threadIdx.x;
  const int b = row / spb, s = row - b * spb;
  const float* xr = x + (size_t)row * D_MODEL;
  unsigned short* orow = out + ((size_t)b * orpb + obase + s) * D_MODEL;

  float4 v0 = *(const float4*)(xr + t * 8);
  float4 v1 = *(const float4*)(xr + t * 8 + 4);
  float sum = v0.x + v0.y + v0.z + v0.w + v1.x + v1.y + v1.z + v1.w;
  float sq  = v0.x*v0.x + v0.y*v0.y + v0.z*v0.z + v0.w*v0.w
            + v1.x*v1.x + v1.y*v1.y + v1.z*v1.z + v1.w*v1.w;
#pragma unroll
  for (int o = 32; o > 0; o >>= 1) {
    sum += __shfl_down(sum, o);
    sq  += __shfl_down(sq, o);
  }
  __shared__ float red[8];
  const int wv = t >> 6, l = t & 63;
  if (l == 0) { red[wv] = sum; red[4 + wv] = sq; }
  __syncthreads();
  sum = red[0] + red[1] + red[2] + red[3];
  sq  = red[4] + red[5] + red[6] + red[7];
  const float mu = sum * (1.0f / 2048.0f);
  const float var = sq * (1.0f / 2048.0f) - mu * mu;
  const float rs = rsqrtf(var + 1e-5f);

  float4 g0 = *(const float4*)(gw + t * 8);
  float4 g1 = *(const float4*)(gw + t * 8 + 4);
  float4 b0 = *(const float4*)(bw + t * 8);
  float4 b1 = *(const float4*)(bw + t * 8 + 4);
  u16x8 r;
  r[0] = f2bf((v0.x - mu) * rs * g0.x + b0.x);
  r[1] = f2bf((v0.y - mu) * rs * g0.y + b0.y);
  r[2] = f2bf((v0.z - mu) * rs * g0.z + b0.z);
  r[3] = f2bf((v0.w - mu) * rs * g0.w + b0.w);
  r[4] = f2bf((v1.x - mu) * rs * g1.x + b1.x);
  r[5] = f2bf((v1.y - mu) * rs * g1.y + b1.y);
  r[6] = f2bf((v1.z - mu) * rs * g1.z + b1.z);
  r[7] = f2bf((v1.w - mu) * rs * g1.w + b1.w);
  *(u16x8*)(orow + t * 8) = r;
}

// ---------------- GEMM 256x256, BK=32, 8 waves, triple-buffer counted-vmcnt ----
// C[M,2048] = A[M,2048] @ W[2048,2048]^T
// mode 0: Q merged   rows<4096 -> dst0 (text), else dst1 (image)
// mode 2: linear f32 dst0[row*2048+col]
// mode 4: KV merged  y==0: K d-swizzled -> dst0 ; y==1: V transposed s-swizzled -> dst1
__global__ __launch_bounds__(512, 2) void gemm256_kernel(
    const unsigned short* __restrict__ A,
    const unsigned short* __restrict__ W0, const unsigned short* __restrict__ W1,
    void* __restrict__ dst0, void* __restrict__ dst1, int mode) {
  __shared__ unsigned short lds[3][2][8192];   // [buf][A=0/B=1][256*32], 96 KB

  const int tid = threadIdx.x;
  const int wid = tid >> 6, l = tid & 63;
  const int wm = wid >> 2, wn = wid & 3;
  const int fr = l & 15, fg = l >> 4;

  // XCD-chunked block swizzle (gridDim.x % 8 == 0)
  const int nwg = gridDim.x, cpx = nwg >> 3;
  const int bid = blockIdx.x;
  const int wg = (bid & 7) * cpx + (bid >> 3);
  const int bm = wg >> 3, bn = wg & 7;     // N = 2048 -> 8 col tiles of 256

  const unsigned short* Wp = W0;
  int m = mode;
  if (mode == 4) { if (blockIdx.y == 0) m = 3; else { m = 1; Wp = W1; } }

  // staging map: thread covers 16B at elem tid*8 of the 256x32 tile (+ row 128 half)
  const int srow = tid >> 2, scol = (tid & 3) * 8;
  const unsigned short* ga = A  + (size_t)(bm * 256 + srow) * 2048 + scol;
  const unsigned short* gb = Wp + (size_t)(bn * 256 + srow) * 2048 + scol;

#define STAGE(buf, kt) do {                                         \
    const int _ko = (kt) * 32;                                      \
    unsigned short* _la = &lds[(buf)][0][wid * 512];                \
    unsigned short* _lb = &lds[(buf)][1][wid * 512];                \
    gload_lds16(ga + _ko,              _la);                        \
    gload_lds16(ga + _ko + 128 * 2048, _la + 4096);                 \
    gload_lds16(gb + _ko,              _lb);                        \
    gload_lds16(gb + _ko + 128 * 2048, _lb + 4096);                 \
  } while (0)

  f32x4 acc[8][4] = {};

  // prologue: tiles 0,1 in flight; wait tile0 (keep tile1's 4 loads pending)
  STAGE(0, 0);
  STAGE(1, 1);
  asm volatile("s_waitcnt vmcnt(4)" ::: "memory");
  __builtin_amdgcn_s_barrier();

  int cur = 0;
  for (int kt = 0; kt < 64; ++kt) {
    // fragment reads from current buffer (bank-balanced: stride 64B rows)
    bf16x8 af[8], bfr[4];
#pragma unroll
    for (int mi = 0; mi < 8; ++mi)
      af[mi] = *(const bf16x8*)&lds[cur][0][(wm * 128 + mi * 16 + fr) * 32 + fg * 8];
#pragma unroll
    for (int ni = 0; ni < 4; ++ni)
      bfr[ni] = *(const bf16x8*)&lds[cur][1][(wn * 64 + ni * 16 + fr) * 32 + fg * 8];

    // prefetch tile kt+2 into buffer (kt+2)%3 (overwrites tile kt-1's buffer)
    if (kt < 62) {
      int sb = cur + 2; if (sb >= 3) sb -= 3;
      STAGE(sb, kt + 2);
    }

    __builtin_amdgcn_s_setprio(1);
#pragma unroll
    for (int mi = 0; mi < 8; ++mi)
#pragma unroll
      for (int ni = 0; ni < 4; ++ni)
        acc[mi][ni] = MFMA16(af[mi], bfr[ni], acc[mi][ni]);
    __builtin_amdgcn_s_setprio(0);

    // counted-vmcnt barrier: tile kt+1 arrival; kt+2's 4 loads stay in flight
    __builtin_amdgcn_sched_barrier(0);
    if (kt < 62) {
      asm volatile("s_waitcnt vmcnt(4)" ::: "memory");
      __builtin_amdgcn_s_barrier();
    } else if (kt < 63) {
      asm volatile("s_waitcnt vmcnt(0)" ::: "memory");
      __builtin_amdgcn_s_barrier();
    }
    ++cur; if (cur >= 3) cur = 0;
  }
#undef STAGE

  // epilogue: scatter per mode
#pragma unroll
  for (int mi = 0; mi < 8; ++mi) {
#pragma unroll
    for (int r = 0; r < 4; ++r) {
      int row = bm * 256 + wm * 128 + mi * 16 + fg * 4 + r;
#pragma unroll
      for (int ni = 0; ni < 4; ++ni) {
        int col = bn * 256 + wn * 64 + ni * 16 + fr;
        float v = acc[mi][ni][r];
        if (m == 2) {
          ((float*)dst0)[(size_t)row * 2048 + col] = v;   // d_out is FLOAT32
        } else if (m == 0) {
          int hh = col >> 7, d = col & 127;
          if (row < 4096) {
            int b = row >> 11, s = row & 2047;
            ((unsigned short*)dst0)[((size_t)(b * NH + hh) * 2048 + s) * 128 + d] = f2bf(v);
          } else {
            int rr = row - 4096, b = rr >> 10, s = rr & 1023;
            ((unsigned short*)dst1)[((size_t)(b * NH + hh) * 1024 + s) * 128 + d] = f2bf(v);
          }
        } else {
          int b = row / 3072, s = row - b * 3072;
          int hh = col >> 7, d = col & 127;
          size_t bh = (size_t)(b * NH + hh);
          if (m == 3) {
            ((unsigned short*)dst0)[(bh * 3072 + s) * 128 + (d ^ ((s & 7) << 3))] = f2bf(v);
          } else {
            int ssw = (s & ~63) | ((s & 63) ^ ((d & 7) << 3));
            ((unsigned short*)dst1)[(bh * 128 + d) * (size_t)3072 + ssw] = f2bf(v);
          }
        }
      }
    }
  }
}

// ---------------- flash attention: text+image merged, swapped-operand ----------------
// grid: 768 blocks (1D). XCD-chunked decode -> (qt24, h, b). qt24<16: text else image.
// 4 waves x 32 q-rows = 128 q/block; KV tile = 64.
__global__ __launch_bounds__(256, 3) void attn_kernel(
    const unsigned short* __restrict__ Qt, const unsigned short* __restrict__ Qi,
    const unsigned short* __restrict__ Kh, const unsigned short* __restrict__ Vt,
    unsigned short* __restrict__ AOt, unsigned short* __restrict__ AOi) {
  __shared__ unsigned short Sh[24576];   // Ks 8192 | Vs 8192 | Ps 4x2048 (shorts)
  unsigned short* Ks = Sh;
  unsigned short* Vs = Sh + 8192;

  const int lin = blockIdx.x;
  const int w768 = (lin & 7) * 96 + (lin >> 3);    // XCD-chunked (768 % 8 == 0)
  const int qt24 = w768 % 24;
  const int hb   = w768 / 24;
  const int h = hb & 15, b = hb >> 4;
  const bool is_text = qt24 < 16;
  const int qt = is_text ? qt24 : qt24 - 16;
  const int Sq = is_text ? 2048 : 1024;
  const unsigned short* Qh = is_text ? Qt : Qi;
  unsigned short* AO = is_text ? AOt : AOi;

  const int tid = threadIdx.x;
  const int w = tid >> 6, l = tid & 63;
  const int fr = l & 15, fg = l >> 4;
  const size_t bh = (size_t)(b * NH + h);
  unsigned short* Pw = Sh + 16384 + w * 2048;      // per-wave P [32 q][64 k]

  const unsigned short* Qbase = Qh + (bh * Sq + (size_t)qt * 128 + w * 32) * HD;
  bf16x8 qf[2][4];
#pragma unroll
  for (int h2 = 0; h2 < 2; ++h2)
#pragma unroll
    for (int c = 0; c < 4; ++c)
      qf[h2][c] = *(const bf16x8*)(Qbase + (h2 * 16 + fr) * HD + c * 32 + fg * 8);

  f32x4 o[2][8] = {};     // O^T: [h2][nt] rows d = nt*16+fg*4+r, col q = fr
  float m[2]    = {-1e30f, -1e30f};
  float lsum[2] = {0.f, 0.f};

  const unsigned short* Kb = Kh + bh * (size_t)SKV * HD;
  const unsigned short* Vb = Vt + bh * (size_t)HD * SKV;

  const int krow = l >> 4, kcol = (l & 15) * 8;  // K chunk: 4 rows x 128
  const int vrow = l >> 3, vcol = (l & 7) * 8;   // V chunk: 8 rows x 64
  const int sw = (fr & 7) << 3;

  for (int kt = 0; kt < SKV / 64; ++kt) {
#pragma unroll
    for (int i = 0; i < 4; ++i) {
      const int ci = w * 4 + i;
      gload_lds16(Kb + (size_t)(kt * 64 + ci * 4 + krow) * HD + kcol, &Ks[ci * 512]);
      gload_lds16(Vb + (size_t)(ci * 8 + vrow) * SKV + kt * 64 + vcol, &Vs[ci * 512]);
    }
    __syncthreads();

    // ---- S^T = K @ Q^T : rows k (j*16+fg*4+r), col q = fr ----
    f32x4 sT[2][4] = {};
#pragma unroll
    for (int j = 0; j < 4; ++j) {
      const int krb = (j * 16 + fr) * 128;
#pragma unroll
      for (int c = 0; c < 4; ++c) {
        bf16x8 kf = *(const bf16x8*)&Ks[krb + ((c * 32 + fg * 8) ^ sw)];
        sT[0][j] = MFMA16(kf, qf[0][c], sT[0][j]);
        sT[1][j] = MFMA16(kf, qf[1][c], sT[1][j]);
      }
    }

    // ---- per-lane softmax (q = fr), defer-max rescale, packed P writes ----
#pragma unroll
    for (int h2 = 0; h2 < 2; ++h2) {
      float tm = sT[h2][0][0];
#pragma unroll
      for (int j = 0; j < 4; ++j)
#pragma unroll
        for (int r = 0; r < 4; ++r) tm = fmaxf(tm, sT[h2][j][r]);
      tm = fmaxf(tm, __shfl_xor(tm, 16));
      tm = fmaxf(tm, __shfl_xor(tm, 32));
      if (__any(tm - m[h2] > 8.0f)) {
        float mn = fmaxf(m[h2], tm);
        float al = __expf(m[h2] - mn);
#pragma unroll
        for (int nt = 0; nt < 8; ++nt) {
          f32x4 t = o[h2][nt];
          t[0] *= al; t[1] *= al; t[2] *= al; t[3] *= al;
          o[h2][nt] = t;
        }
        lsum[h2] *= al;
        m[h2] = mn;
      }
      const float mm = m[h2];
      float ps = 0.f;
      unsigned short* prow = &Pw[(h2 * 16 + fr) * 64];
#pragma unroll
      for (int j = 0; j < 4; ++j) {
        u16x4 pk;
#pragma unroll
        for (int r = 0; r < 4; ++r) {
          float p = __expf(sT[h2][j][r] - mm);
          ps += p;
          pk[r] = f2bf(p);
        }
        *reinterpret_cast<u16x4*>(&prow[(16 * j + fg * 4) ^ sw]) = pk;
      }
      lsum[h2] += ps;
    }

    asm volatile("s_waitcnt lgkmcnt(0)" ::: "memory");
    __builtin_amdgcn_sched_barrier(0);

    // ---- O^T += V^T @ P^T ----
    bf16x8 pb[2][2];
#pragma unroll
    for (int h2 = 0; h2 < 2; ++h2)
#pragma unroll
      for (int kc = 0; kc < 2; ++kc)
        pb[h2][kc] = *(const bf16x8*)&Pw[(h2 * 16 + fr) * 64 + ((kc * 32 + fg * 8) ^ sw)];
#pragma unroll
    for (int nt = 0; nt < 8; ++nt) {
      const int vrb = (nt * 16 + fr) * 64;
#pragma unroll
      for (int kc = 0; kc < 2; ++kc) {
        bf16x8 vf = *(const bf16x8*)&Vs[vrb + ((kc * 32 + fg * 8) ^ sw)];
        o[0][nt] = MFMA16(vf, pb[0][kc], o[0][nt]);
        o[1][nt] = MFMA16(vf, pb[1][kc], o[1][nt]);
      }
    }
    __syncthreads();
  }

  // ---- epilogue: reduce lsum across fg, transpose O^T via LDS, coalesced store ----
  float inv[2];
#pragma unroll
  for (int h2 = 0; h2 < 2; ++h2) {
    float t = lsum[h2];
    t += __shfl_xor(t, 16);
    t += __shfl_xor(t, 32);
    inv[h2] = 1.0f / t;
  }
  unsigned short* Os = &Sh[w * 4096];   // per-wave [32 q][128 d]
#pragma unroll
  for (int h2 = 0; h2 < 2; ++h2) {
    unsigned short* orow = &Os[(h2 * 16 + fr) * 128];
#pragma unroll
    for (int nt = 0; nt < 8; ++nt) {
      u16x4 pk;
#pragma unroll
      for (int r = 0; r < 4; ++r) pk[r] = f2bf(o[h2][nt][r] * inv[h2]);
      *reinterpret_cast<u16x4*>(&orow[(nt * 16 + fg * 4) ^ sw]) = pk;
    }
  }
  asm volatile("s_waitcnt lgkmcnt(0)" ::: "memory");
  __builtin_amdgcn_sched_barrier(0);
  const int qr4 = l >> 4;
  const int dc = (l & 15) * 8;
  unsigned short* AObase = AO + ((size_t)b * Sq + (size_t)qt * 128 + w * 32) * D_MODEL + h * HD;
#pragma unroll
  for (int g = 0; g < 8; ++g) {
    const int row = g * 4 + qr4;
    bf16x8 v = *reinterpret_cast<const bf16x8*>(&Os[row * 128 + (dc ^ ((row & 7) << 3))]);
    *reinterpret_cast<bf16x8*>(&AObase[(size_t)row * D_MODEL + dc]) = v;
  }
}

// ---------------- host launch ----------------
extern "C" void kernel_launch(void* const* d_in, const int* in_sizes, int n_in,
                              void* d_out, int out_size, void* d_ws, size_t ws_size,
                              hipStream_t stream) {
  const float* q_text  = (const float*)d_in[0];
  const float* q_image = (const float*)d_in[1];
  const float* k_text  = (const float*)d_in[2];
  const float* k_image = (const float*)d_in[3];
  const float* Wq = (const float*)d_in[4];
  const float* Wk = (const float*)d_in[5];
  const float* Wv = (const float*)d_in[6];
  const float* Wo = (const float*)d_in[7];
  const float* ln_tg = (const float*)d_in[8];
  const float* ln_tb = (const float*)d_in[9];
  const float* ln_ig = (const float*)d_in[10];
  const float* ln_ib = (const float*)d_in[11];

  // workspace layout (bf16 elements)
  unsigned short* wq  = (unsigned short*)d_ws;
  unsigned short* wk  = wq  + 4194304;
  unsigned short* wv  = wk  + 4194304;
  unsigned short* wo  = wv  + 4194304;
  unsigned short* xqt = wo  + 4194304;   // LN'd q_text  [4096,2048]; later AO_text
  unsigned short* xqi = xqt + 8388608;   // LN'd q_image [2048,2048]; later AO_image
  unsigned short* xk  = xqi + 4194304;   // LN'd concat k [2,3072,2048]
  unsigned short* qht = xk  + 12582912;  // [2,16,2048,128]
  unsigned short* qhi = qht + 8388608;   // [2,16,1024,128]
  unsigned short* kh  = qhi + 4194304;   // [2,16,3072,128] (d-swizzled)
  unsigned short* vt  = kh  + 12582912;  // [2,16,128,3072] (s-swizzled)
  const size_t needed = (size_t)(vt + 12582912 - wq) * 2;
  if (ws_size < needed) return;

  // weights -> bf16 (fold softmax scale into Wq), one dispatch
  cvt_w_kernel<<<dim3(2048, 4), 256, 0, stream>>>(Wq, Wk, Wv, Wo, wq);

  // LayerNorms
  ln_kernel<<<4096, 256, 0, stream>>>(q_text,  ln_tg, ln_tb, xqt, 2048, 2048, 0);
  ln_kernel<<<2048, 256, 0, stream>>>(q_image, ln_ig, ln_ib, xqi, 1024, 1024, 0);
  ln_kernel<<<4096, 256, 0, stream>>>(k_text,  ln_tg, ln_tb, xk, 2048, 3072, 0);
  ln_kernel<<<2048, 256, 0, stream>>>(k_image, ln_ig, ln_ib, xk, 1024, 3072, 2048);

  // projections: Q (M=6144), K+V (merged via grid.y) — 256^2 tiles
  gemm256_kernel<<<192, 512, 0, stream>>>(xqt, wq, nullptr, qht, qhi, 0);
  gemm256_kernel<<<dim3(192, 2), 512, 0, stream>>>(xk, wk, wv, kh, vt, 4);

  // attention: text+image in one dispatch
  attn_kernel<<<768, 256, 0, stream>>>(qht, qhi, kh, vt, xqt, xqi);

  // output projection: M=6144 straight into FLOAT32 d_out
  gemm256_kernel<<<192, 512, 0, stream>>>(xqt, wo, nullptr, d_out, nullptr, 2);
}

// Round 8
// 531.847 us; speedup vs baseline: 1.9864x; 1.0126x over previous
//
#include <hip/hip_runtime.h>

// ---------------- types / helpers ----------------
typedef __attribute__((ext_vector_type(8))) short bf16x8;   // 8 bf16 (4 VGPRs)
typedef __attribute__((ext_vector_type(4))) float f32x4;    // MFMA accum
typedef __attribute__((ext_vector_type(8))) unsigned short u16x8;

#define D_MODEL 2048
#define NH 16
#define HD 128
#define SKV 3072
#define QK_SCALE 0.08838834764831845f  // 128^-0.5
#define LOG2E 1.4426950408889634f
#define DEFER_THR 11.5413f             // 8 * log2(e)

__device__ __forceinline__ unsigned short f2bf(float f) {
  unsigned int u = __float_as_uint(f);
  u += 0x7fffu + ((u >> 16) & 1u);     // RNE, finite inputs only
  return (unsigned short)(u >> 16);
}
__device__ __forceinline__ float exp2hw(float x) {
  float r; asm("v_exp_f32 %0, %1" : "=v"(r) : "v"(x)); return r;
}
__device__ __forceinline__ unsigned int cvtpk(float lo, float hi) {
  unsigned int r; asm("v_cvt_pk_bf16_f32 %0, %1, %2" : "=v"(r) : "v"(lo), "v"(hi)); return r;
}

typedef __attribute__((address_space(1))) void as1_void;
typedef __attribute__((address_space(3))) void as3_void;
__device__ __forceinline__ void gload_lds16(const void* g, void* l) {
  __builtin_amdgcn_global_load_lds((as1_void*)g, (as3_void*)l, 16, 0, 0);
}

#define MFMA16(a, b, c) __builtin_amdgcn_mfma_f32_16x16x32_bf16((a), (b), (c), 0, 0, 0)

// ---------------- weight convert: all 4 weights in one dispatch ----------------
__global__ __launch_bounds__(256) void cvt_w_kernel(
    const float* __restrict__ s0, const float* __restrict__ s1,
    const float* __restrict__ s2, const float* __restrict__ s3,
    unsigned short* __restrict__ dstbase) {
  const int y = blockIdx.y;
  const float* src = (y == 0) ? s0 : (y == 1) ? s1 : (y == 2) ? s2 : s3;
  const float scale = (y == 0) ? (QK_SCALE * LOG2E) : 1.0f;   // fold softmax+log2e into Wq
  unsigned short* dst = dstbase + (size_t)y * 4194304;
  int i = blockIdx.x * 256 + threadIdx.x;
  const float4* s = (const float4*)src + (size_t)i * 2;
  float4 a = s[0], b = s[1];
  u16x8 r;
  r[0] = f2bf(a.x * scale); r[1] = f2bf(a.y * scale);
  r[2] = f2bf(a.z * scale); r[3] = f2bf(a.w * scale);
  r[4] = f2bf(b.x * scale); r[5] = f2bf(b.y * scale);
  r[6] = f2bf(b.z * scale); r[7] = f2bf(b.w * scale);
  *((u16x8*)dst + i) = r;
}

// ---------------- LayerNorm -> bf16 (with row remap for K concat) ----------------
__global__ __launch_bounds__(256) void ln_kernel(
    const float* __restrict__ x, const float* __restrict__ gw,
    const float* __restrict__ bw, unsigned short* __restrict__ out,
    int spb, int orpb, int obase) {
  const int row = blockIdx.x;
  const int t = threadIdx.x;
  const int b = row / spb, s = row - b * spb;
  const float* xr = x + (size_t)row * D_MODEL;
  unsigned short* orow = out + ((size_t)b * orpb + obase + s) * D_MODEL;

  float4 v0 = *(const float4*)(xr + t * 8);
  float4 v1 = *(const float4*)(xr + t * 8 + 4);
  float sum = v0.x + v0.y + v0.z + v0.w + v1.x + v1.y + v1.z + v1.w;
  float sq  = v0.x*v0.x + v0.y*v0.y + v0.z*v0.z + v0.w*v0.w
            + v1.x*v1.x + v1.y*v1.y + v1.z*v1.z + v1.w*v1.w;
#pragma unroll
  for (int o = 32; o > 0; o >>= 1) {
    sum += __shfl_down(sum, o);
    sq  += __shfl_down(sq, o);
  }
  __shared__ float red[8];
  const int wv = t >> 6, l = t & 63;
  if (l == 0) { red[wv] = sum; red[4 + wv] = sq; }
  __syncthreads();
  sum = red[0] + red[1] + red[2] + red[3];
  sq  = red[4] + red[5] + red[6] + red[7];
  const float mu = sum * (1.0f / 2048.0f);
  const float var = sq * (1.0f / 2048.0f) - mu * mu;
  const float rs = rsqrtf(var + 1e-5f);

  float4 g0 = *(const float4*)(gw + t * 8);
  float4 g1 = *(const float4*)(gw + t * 8 + 4);
  float4 b0 = *(const float4*)(bw + t * 8);
  float4 b1 = *(const float4*)(bw + t * 8 + 4);
  u16x8 r;
  r[0] = f2bf((v0.x - mu) * rs * g0.x + b0.x);
  r[1] = f2bf((v0.y - mu) * rs * g0.y + b0.y);
  r[2] = f2bf((v0.z - mu) * rs * g0.z + b0.z);
  r[3] = f2bf((v0.w - mu) * rs * g0.w + b0.w);
  r[4] = f2bf((v1.x - mu) * rs * g1.x + b1.x);
  r[5] = f2bf((v1.y - mu) * rs * g1.y + b1.y);
  r[6] = f2bf((v1.z - mu) * rs * g1.z + b1.z);
  r[7] = f2bf((v1.w - mu) * rs * g1.w + b1.w);
  *(u16x8*)(orow + t * 8) = r;
}

// ---------------- GEMM 128x128, BK=32, 4 waves, triple-buffer counted-vmcnt ----
// mode 10: QKV merged (2304 tiles: mat = tile/768; Q->split qht/qhi, K->d-swz, V->t+s-swz)
// mode 2 : linear f32 (out projection, 768 tiles)
__global__ __launch_bounds__(256, 3) void gemm128_kernel(
    const unsigned short* __restrict__ Aq, const unsigned short* __restrict__ Akv,
    const unsigned short* __restrict__ Wq, const unsigned short* __restrict__ Wk,
    const unsigned short* __restrict__ Wv,
    void* __restrict__ d0, void* __restrict__ d1,
    void* __restrict__ d2, void* __restrict__ d3, int mode) {
  __shared__ unsigned short lds[3][2][4096];   // [buf][A|B][128*32] = 48 KB

  const int tid = threadIdx.x;
  const int wid = tid >> 6, l = tid & 63;
  const int wm = wid >> 1, wn = wid & 1;
  const int fr = l & 15, fg = l >> 4;

  // XCD-chunked swizzle (grid % 8 == 0)
  const int cpx = gridDim.x >> 3;
  int wg = (blockIdx.x & 7) * cpx + (blockIdx.x >> 3);

  const unsigned short* A = Aq;
  const unsigned short* W = Wq;
  int emode = mode;
  if (mode == 10) {
    int mat = wg / 768; wg -= mat * 768;
    if (mat == 0)      { emode = 0; }
    else if (mat == 1) { emode = 3; A = Akv; W = Wk; }
    else               { emode = 1; A = Akv; W = Wv; }
  }
  const int bm = wg >> 4, bn = wg & 15;   // 16 col-tiles of 128

  const unsigned short* ga = A + (size_t)(bm * 128 + wid * 32 + (l >> 2)) * 2048 + (l & 3) * 8;
  const unsigned short* gb = W + (size_t)(bn * 128 + wid * 32 + (l >> 2)) * 2048 + (l & 3) * 8;

#define STAGE(buf, kt) do {                                   \
    const int _ko = (kt) * 32;                                \
    unsigned short* _la = &lds[(buf)][0][wid * 1024];         \
    unsigned short* _lb = &lds[(buf)][1][wid * 1024];         \
    gload_lds16(ga + _ko,             _la);                   \
    gload_lds16(ga + _ko + 16 * 2048, _la + 512);             \
    gload_lds16(gb + _ko,             _lb);                   \
    gload_lds16(gb + _ko + 16 * 2048, _lb + 512);             \
  } while (0)

  f32x4 acc[4][4] = {};

  STAGE(0, 0);
  STAGE(1, 1);
  asm volatile("s_waitcnt vmcnt(4)" ::: "memory");
  __builtin_amdgcn_s_barrier();

  int cur = 0;
  for (int kt = 0; kt < 64; ++kt) {
    bf16x8 af[4], bfr[4];
#pragma unroll
    for (int mi = 0; mi < 4; ++mi)
      af[mi] = *(const bf16x8*)&lds[cur][0][(wm * 64 + mi * 16 + fr) * 32 + fg * 8];
#pragma unroll
    for (int ni = 0; ni < 4; ++ni)
      bfr[ni] = *(const bf16x8*)&lds[cur][1][(wn * 64 + ni * 16 + fr) * 32 + fg * 8];

    if (kt < 62) {
      int sb = cur + 2; if (sb >= 3) sb -= 3;
      STAGE(sb, kt + 2);
    }

    __builtin_amdgcn_s_setprio(1);
#pragma unroll
    for (int mi = 0; mi < 4; ++mi)
#pragma unroll
      for (int ni = 0; ni < 4; ++ni)
        acc[mi][ni] = MFMA16(af[mi], bfr[ni], acc[mi][ni]);
    __builtin_amdgcn_s_setprio(0);

    __builtin_amdgcn_sched_barrier(0);
    if (kt < 62) {
      asm volatile("s_waitcnt vmcnt(4)" ::: "memory");
      __builtin_amdgcn_s_barrier();
    } else if (kt < 63) {
      asm volatile("s_waitcnt vmcnt(0)" ::: "memory");
      __builtin_amdgcn_s_barrier();
    }
    ++cur; if (cur >= 3) cur = 0;
  }
#undef STAGE

#pragma unroll
  for (int mi = 0; mi < 4; ++mi) {
#pragma unroll
    for (int r = 0; r < 4; ++r) {
      int row = bm * 128 + wm * 64 + mi * 16 + fg * 4 + r;
#pragma unroll
      for (int ni = 0; ni < 4; ++ni) {
        int col = bn * 128 + wn * 64 + ni * 16 + fr;
        float v = acc[mi][ni][r];
        if (emode == 2) {
          ((float*)d0)[(size_t)row * 2048 + col] = v;   // d_out is FLOAT32
        } else if (emode == 0) {
          int hh = col >> 7, d = col & 127;
          if (row < 4096) {
            int b = row >> 11, s = row & 2047;
            ((unsigned short*)d0)[((size_t)(b * NH + hh) * 2048 + s) * 128 + d] = f2bf(v);
          } else {
            int rr = row - 4096, b = rr >> 10, s = rr & 1023;
            ((unsigned short*)d1)[((size_t)(b * NH + hh) * 1024 + s) * 128 + d] = f2bf(v);
          }
        } else {
          int b = row / 3072, s = row - b * 3072;
          int hh = col >> 7, d = col & 127;
          size_t bh = (size_t)(b * NH + hh);
          if (emode == 3) {
            ((unsigned short*)d2)[(bh * 3072 + s) * 128 + (d ^ ((s & 7) << 3))] = f2bf(v);
          } else {
            int ssw = (s & ~31) | ((s & 31) ^ ((d & 3) << 3));   // 32-wide groups
            ((unsigned short*)d3)[(bh * 128 + d) * (size_t)3072 + ssw] = f2bf(v);
          }
        }
      }
    }
  }
}

// ---------------- flash attention: dbuf K/V, KVBLK=32, counted-vmcnt -------------
// grid 768 (XCD-chunked). 4 waves x 32 q. LDS: Ks[2]16KB | Vs[2]16KB | P 8KB = 40KB.
__global__ __launch_bounds__(256, 3) void attn_kernel(
    const unsigned short* __restrict__ Qt, const unsigned short* __restrict__ Qi,
    const unsigned short* __restrict__ Kh, const unsigned short* __restrict__ Vt,
    unsigned short* __restrict__ AOt, unsigned short* __restrict__ AOi) {
  __shared__ unsigned short Sh[20480];  // Ks0|Ks1|Vs0|Vs1|P(4x1024)

  const int lin = blockIdx.x;
  const int w768 = (lin & 7) * 96 + (lin >> 3);
  const int qt24 = w768 % 24;
  const int hb   = w768 / 24;
  const int h = hb & 15, b = hb >> 4;
  const bool is_text = qt24 < 16;
  const int qt = is_text ? qt24 : qt24 - 16;
  const int Sq = is_text ? 2048 : 1024;
  const unsigned short* Qh = is_text ? Qt : Qi;
  unsigned short* AO = is_text ? AOt : AOi;

  const int tid = threadIdx.x;
  const int w = tid >> 6, l = tid & 63;
  const int fr = l & 15, fg = l >> 4;
  const size_t bh = (size_t)(b * NH + h);
  unsigned short* Pw = Sh + 16384 + w * 1024;   // per-wave [32 q][32 k]

  const unsigned short* Qbase = Qh + (bh * Sq + (size_t)qt * 128 + w * 32) * HD;
  bf16x8 qf[2][4];
#pragma unroll
  for (int h2 = 0; h2 < 2; ++h2)
#pragma unroll
    for (int c = 0; c < 4; ++c)
      qf[h2][c] = *(const bf16x8*)(Qbase + (h2 * 16 + fr) * HD + c * 32 + fg * 8);

  f32x4 o[2][8] = {};
  float m[2]    = {-1e30f, -1e30f};
  float lsum[2] = {0.f, 0.f};

  const unsigned short* Kb = Kh + bh * (size_t)SKV * HD;
  const unsigned short* Vb = Vt + bh * (size_t)HD * SKV;

  const int swk = (fr & 7) << 3;   // K d-swizzle (within 128)
  const int swv = (fr & 3) << 3;   // V s-swizzle (within 32) + P swizzle

  // stage macros: 2 gloads each (wave covers its quarter)
#define STAGE_K(kt, half) do {                                                   \
    unsigned short* _d = Sh + (half) * 4096 + w * 1024;                          \
    const unsigned short* _s = Kb + (size_t)((kt) * 32 + w * 8 + (l >> 4)) * 128 \
                               + (l & 15) * 8;                                   \
    gload_lds16(_s, _d);                                                         \
    gload_lds16(_s + 4 * 128, _d + 512);                                         \
  } while (0)
#define STAGE_V(kt, half) do {                                                   \
    unsigned short* _d = Sh + 8192 + (half) * 4096 + w * 1024;                   \
    const unsigned short* _s = Vb + (size_t)(w * 32 + (l >> 2)) * SKV            \
                               + (kt) * 32 + (l & 3) * 8;                        \
    gload_lds16(_s, _d);                                                         \
    gload_lds16(_s + 16 * SKV, _d + 512);                                        \
  } while (0)

  STAGE_K(0, 0);
  for (int kt = 0; kt < 96; ++kt) {
    const int half = kt & 1;
    STAGE_V(kt, half);
    asm volatile("s_waitcnt vmcnt(2)" ::: "memory");   // K(kt) ready; V(kt) in flight
    __builtin_amdgcn_s_barrier();

    // ---- S^T = K @ Q^T : rows k = j*16+fg*4+r, col q = fr ----
    const unsigned short* Ksc = Sh + half * 4096;
    f32x4 sT[2][2] = {};
#pragma unroll
    for (int j = 0; j < 2; ++j) {
      const int krb = (j * 16 + fr) * 128;
#pragma unroll
      for (int c = 0; c < 4; ++c) {
        bf16x8 kf = *(const bf16x8*)&Ksc[krb + ((c * 32 + fg * 8) ^ swk)];
        sT[0][j] = MFMA16(kf, qf[0][c], sT[0][j]);
        sT[1][j] = MFMA16(kf, qf[1][c], sT[1][j]);
      }
    }
    if (kt < 95) STAGE_K(kt + 1, half ^ 1);

    // ---- per-lane softmax in log2 domain; defer-max; packed P writes ----
#pragma unroll
    for (int h2 = 0; h2 < 2; ++h2) {
      float tm = fmaxf(fmaxf(fmaxf(sT[h2][0][0], sT[h2][0][1]),
                             fmaxf(sT[h2][0][2], sT[h2][0][3])),
                       fmaxf(fmaxf(sT[h2][1][0], sT[h2][1][1]),
                             fmaxf(sT[h2][1][2], sT[h2][1][3])));
      tm = fmaxf(tm, __shfl_xor(tm, 16));
      tm = fmaxf(tm, __shfl_xor(tm, 32));
      if (__any(tm - m[h2] > DEFER_THR)) {
        float mn = fmaxf(m[h2], tm);
        float al = exp2hw(m[h2] - mn);
#pragma unroll
        for (int nt = 0; nt < 8; ++nt) {
          f32x4 t = o[h2][nt];
          t[0] *= al; t[1] *= al; t[2] *= al; t[3] *= al;
          o[h2][nt] = t;
        }
        lsum[h2] *= al;
        m[h2] = mn;
      }
      const float mm = m[h2];
      float p00 = exp2hw(sT[h2][0][0] - mm), p01 = exp2hw(sT[h2][0][1] - mm);
      float p02 = exp2hw(sT[h2][0][2] - mm), p03 = exp2hw(sT[h2][0][3] - mm);
      float p10 = exp2hw(sT[h2][1][0] - mm), p11 = exp2hw(sT[h2][1][1] - mm);
      float p12 = exp2hw(sT[h2][1][2] - mm), p13 = exp2hw(sT[h2][1][3] - mm);
      lsum[h2] += (p00 + p01 + p02 + p03) + (p10 + p11 + p12 + p13);
      unsigned short* prow = &Pw[(h2 * 16 + fr) * 32];
      uint2 w0; w0.x = cvtpk(p00, p01); w0.y = cvtpk(p02, p03);
      uint2 w1; w1.x = cvtpk(p10, p11); w1.y = cvtpk(p12, p13);
      *(uint2*)(prow + ((fg * 4) ^ swv))      = w0;
      *(uint2*)(prow + ((16 + fg * 4) ^ swv)) = w1;
    }

    if (kt < 95) asm volatile("s_waitcnt vmcnt(2)" ::: "memory");  // V(kt) ready; K(kt+1) in flight
    else         asm volatile("s_waitcnt vmcnt(0)" ::: "memory");
    __builtin_amdgcn_s_barrier();

    // wave-local P write->read ordering (rule 18)
    asm volatile("s_waitcnt lgkmcnt(0)" ::: "memory");
    __builtin_amdgcn_sched_barrier(0);

    // ---- O^T += V^T @ P^T ----
    const unsigned short* Vsc = Sh + 8192 + half * 4096;
    bf16x8 pb[2];
#pragma unroll
    for (int h2 = 0; h2 < 2; ++h2)
      pb[h2] = *(const bf16x8*)&Pw[(h2 * 16 + fr) * 32 + ((fg * 8) ^ swv)];
#pragma unroll
    for (int nt = 0; nt < 8; ++nt) {
      bf16x8 vf = *(const bf16x8*)&Vsc[(nt * 16 + fr) * 32 + ((fg * 8) ^ swv)];
      o[0][nt] = MFMA16(vf, pb[0], o[0][nt]);
      o[1][nt] = MFMA16(vf, pb[1], o[1][nt]);
    }
    __builtin_amdgcn_s_barrier();   // all reads of this half done before re-stage
  }
#undef STAGE_K
#undef STAGE_V

  // ---- epilogue: reduce lsum across fg, transpose O^T via LDS, coalesced store ----
  float inv[2];
#pragma unroll
  for (int h2 = 0; h2 < 2; ++h2) {
    float t = lsum[h2];
    t += __shfl_xor(t, 16);
    t += __shfl_xor(t, 32);
    inv[h2] = 1.0f / t;
  }
  unsigned short* Os = &Sh[w * 4096];   // per-wave [32 q][128 d]
#pragma unroll
  for (int h2 = 0; h2 < 2; ++h2) {
    unsigned short* orow = &Os[(h2 * 16 + fr) * 128];
    const int sw8 = (fr & 7) << 3;
#pragma unroll
    for (int nt = 0; nt < 8; ++nt) {
      uint2 pk;
      pk.x = cvtpk(o[h2][nt][0] * inv[h2], o[h2][nt][1] * inv[h2]);
      pk.y = cvtpk(o[h2][nt][2] * inv[h2], o[h2][nt][3] * inv[h2]);
      *(uint2*)(orow + ((nt * 16 + fg * 4) ^ sw8)) = pk;
    }
  }
  asm volatile("s_waitcnt lgkmcnt(0)" ::: "memory");
  __builtin_amdgcn_sched_barrier(0);
  const int qr4 = l >> 4;
  const int dc = (l & 15) * 8;
  unsigned short* AObase = AO + ((size_t)b * Sq + (size_t)qt * 128 + w * 32) * D_MODEL + h * HD;
#pragma unroll
  for (int g = 0; g < 8; ++g) {
    const int row = g * 4 + qr4;
    bf16x8 v = *reinterpret_cast<const bf16x8*>(&Os[row * 128 + (dc ^ ((row & 7) << 3))]);
    *reinterpret_cast<bf16x8*>(&AObase[(size_t)row * D_MODEL + dc]) = v;
  }
}

// ---------------- host launch ----------------
extern "C" void kernel_launch(void* const* d_in, const int* in_sizes, int n_in,
                              void* d_out, int out_size, void* d_ws, size_t ws_size,
                              hipStream_t stream) {
  const float* q_text  = (const float*)d_in[0];
  const float* q_image = (const float*)d_in[1];
  const float* k_text  = (const float*)d_in[2];
  const float* k_image = (const float*)d_in[3];
  const float* Wq = (const float*)d_in[4];
  const float* Wk = (const float*)d_in[5];
  const float* Wv = (const float*)d_in[6];
  const float* Wo = (const float*)d_in[7];
  const float* ln_tg = (const float*)d_in[8];
  const float* ln_tb = (const float*)d_in[9];
  const float* ln_ig = (const float*)d_in[10];
  const float* ln_ib = (const float*)d_in[11];

  // workspace layout (bf16 elements)
  unsigned short* wq  = (unsigned short*)d_ws;
  unsigned short* wk  = wq  + 4194304;
  unsigned short* wv  = wk  + 4194304;
  unsigned short* wo  = wv  + 4194304;
  unsigned short* xqt = wo  + 4194304;   // LN'd q_text  [4096,2048]; later AO_text
  unsigned short* xqi = xqt + 8388608;   // LN'd q_image [2048,2048]; later AO_image
  unsigned short* xk  = xqi + 4194304;   // LN'd concat k [2,3072,2048]
  unsigned short* qht = xk  + 12582912;  // [2,16,2048,128]
  unsigned short* qhi = qht + 8388608;   // [2,16,1024,128]
  unsigned short* kh  = qhi + 4194304;   // [2,16,3072,128] (d-swizzled)
  unsigned short* vt  = kh  + 12582912;  // [2,16,128,3072] (s-swizzled, 32-groups)
  const size_t needed = (size_t)(vt + 12582912 - wq) * 2;
  if (ws_size < needed) return;

  cvt_w_kernel<<<dim3(2048, 4), 256, 0, stream>>>(Wq, Wk, Wv, Wo, wq);

  ln_kernel<<<4096, 256, 0, stream>>>(q_text,  ln_tg, ln_tb, xqt, 2048, 2048, 0);
  ln_kernel<<<2048, 256, 0, stream>>>(q_image, ln_ig, ln_ib, xqi, 1024, 1024, 0);
  ln_kernel<<<4096, 256, 0, stream>>>(k_text,  ln_tg, ln_tb, xk, 2048, 3072, 0);
  ln_kernel<<<2048, 256, 0, stream>>>(k_image, ln_ig, ln_ib, xk, 1024, 3072, 2048);

  // Q+K+V in ONE dispatch: 2304 blocks = exactly 3 resident rounds at 3 blocks/CU
  gemm128_kernel<<<2304, 256, 0, stream>>>(xqt, xk, wq, wk, wv, qht, qhi, kh, vt, 10);

  attn_kernel<<<768, 256, 0, stream>>>(qht, qhi, kh, vt, xqt, xqi);

  // out projection: 768 blocks = exactly 3 rounds, f32 straight into d_out
  gemm128_kernel<<<768, 256, 0, stream>>>(xqt, nullptr, wo, nullptr, nullptr,
                                          d_out, nullptr, nullptr, nullptr, 2);
}

// Round 9
// 499.349 us; speedup vs baseline: 2.1157x; 1.0651x over previous
//
#include <hip/hip_runtime.h>

// ---------------- types / helpers ----------------
typedef __attribute__((ext_vector_type(8))) short bf16x8;   // 8 bf16 (4 VGPRs)
typedef __attribute__((ext_vector_type(4))) float f32x4;    // MFMA accum
typedef __attribute__((ext_vector_type(8))) unsigned short u16x8;

#define D_MODEL 2048
#define NH 16
#define HD 128
#define SKV 3072
#define QK_SCALE 0.08838834764831845f  // 128^-0.5
#define LOG2E 1.4426950408889634f
#define DEFER_THR 11.5413f             // 8 * log2(e)

__device__ __forceinline__ unsigned short f2bf(float f) {
  unsigned int u = __float_as_uint(f);
  u += 0x7fffu + ((u >> 16) & 1u);     // RNE, finite inputs only
  return (unsigned short)(u >> 16);
}
__device__ __forceinline__ float exp2hw(float x) {
  float r; asm("v_exp_f32 %0, %1" : "=v"(r) : "v"(x)); return r;
}
__device__ __forceinline__ unsigned int cvtpk(float lo, float hi) {
  unsigned int r; asm("v_cvt_pk_bf16_f32 %0, %1, %2" : "=v"(r) : "v"(lo), "v"(hi)); return r;
}

typedef __attribute__((address_space(1))) void as1_void;
typedef __attribute__((address_space(3))) void as3_void;
__device__ __forceinline__ void gload_lds16(const void* g, void* l) {
  __builtin_amdgcn_global_load_lds((as1_void*)g, (as3_void*)l, 16, 0, 0);
}

#define MFMA16(a, b, c) __builtin_amdgcn_mfma_f32_16x16x32_bf16((a), (b), (c), 0, 0, 0)

// ---------------- weight convert: all 4 weights in one dispatch ----------------
__global__ __launch_bounds__(256) void cvt_w_kernel(
    const float* __restrict__ s0, const float* __restrict__ s1,
    const float* __restrict__ s2, const float* __restrict__ s3,
    unsigned short* __restrict__ dstbase) {
  const int y = blockIdx.y;
  const float* src = (y == 0) ? s0 : (y == 1) ? s1 : (y == 2) ? s2 : s3;
  const float scale = (y == 0) ? (QK_SCALE * LOG2E) : 1.0f;   // fold softmax+log2e into Wq
  unsigned short* dst = dstbase + (size_t)y * 4194304;
  int i = blockIdx.x * 256 + threadIdx.x;
  const float4* s = (const float4*)src + (size_t)i * 2;
  float4 a = s[0], b = s[1];
  u16x8 r;
  r[0] = f2bf(a.x * scale); r[1] = f2bf(a.y * scale);
  r[2] = f2bf(a.z * scale); r[3] = f2bf(a.w * scale);
  r[4] = f2bf(b.x * scale); r[5] = f2bf(b.y * scale);
  r[6] = f2bf(b.z * scale); r[7] = f2bf(b.w * scale);
  *((u16x8*)dst + i) = r;
}

// ---------------- LayerNorm -> bf16 (with row remap for K concat) ----------------
__global__ __launch_bounds__(256) void ln_kernel(
    const float* __restrict__ x, const float* __restrict__ gw,
    const float* __restrict__ bw, unsigned short* __restrict__ out,
    int spb, int orpb, int obase) {
  const int row = blockIdx.x;
  const int t = threadIdx.x;
  const int b = row / spb, s = row - b * spb;
  const float* xr = x + (size_t)row * D_MODEL;
  unsigned short* orow = out + ((size_t)b * orpb + obase + s) * D_MODEL;

  float4 v0 = *(const float4*)(xr + t * 8);
  float4 v1 = *(const float4*)(xr + t * 8 + 4);
  float sum = v0.x + v0.y + v0.z + v0.w + v1.x + v1.y + v1.z + v1.w;
  float sq  = v0.x*v0.x + v0.y*v0.y + v0.z*v0.z + v0.w*v0.w
            + v1.x*v1.x + v1.y*v1.y + v1.z*v1.z + v1.w*v1.w;
#pragma unroll
  for (int o = 32; o > 0; o >>= 1) {
    sum += __shfl_down(sum, o);
    sq  += __shfl_down(sq, o);
  }
  __shared__ float red[8];
  const int wv = t >> 6, l = t & 63;
  if (l == 0) { red[wv] = sum; red[4 + wv] = sq; }
  __syncthreads();
  sum = red[0] + red[1] + red[2] + red[3];
  sq  = red[4] + red[5] + red[6] + red[7];
  const float mu = sum * (1.0f / 2048.0f);
  const float var = sq * (1.0f / 2048.0f) - mu * mu;
  const float rs = rsqrtf(var + 1e-5f);

  float4 g0 = *(const float4*)(gw + t * 8);
  float4 g1 = *(const float4*)(gw + t * 8 + 4);
  float4 b0 = *(const float4*)(bw + t * 8);
  float4 b1 = *(const float4*)(bw + t * 8 + 4);
  u16x8 r;
  r[0] = f2bf((v0.x - mu) * rs * g0.x + b0.x);
  r[1] = f2bf((v0.y - mu) * rs * g0.y + b0.y);
  r[2] = f2bf((v0.z - mu) * rs * g0.z + b0.z);
  r[3] = f2bf((v0.w - mu) * rs * g0.w + b0.w);
  r[4] = f2bf((v1.x - mu) * rs * g1.x + b1.x);
  r[5] = f2bf((v1.y - mu) * rs * g1.y + b1.y);
  r[6] = f2bf((v1.z - mu) * rs * g1.z + b1.z);
  r[7] = f2bf((v1.w - mu) * rs * g1.w + b1.w);
  *(u16x8*)(orow + t * 8) = r;
}

// ---------------- GEMM 256x256, BK=64, 8 waves, 4-phase dbuf counted-vmcnt ------
// LDS 128KB: [buf][ A 256x64 (2 halves of 128 rows) | B 256x64 ], XOR-swizzled.
// mode 10: QKV merged (576 tiles: mat=wg/192; Q->split d0/d1, K->d-swz d2, V->t+s-swz d3)
// mode 2 : linear f32 d0 (out projection, 192 tiles)
__global__ __launch_bounds__(512, 2) void gemm256p_kernel(
    const unsigned short* __restrict__ Aq, const unsigned short* __restrict__ Akv,
    const unsigned short* __restrict__ Wq, const unsigned short* __restrict__ Wk,
    const unsigned short* __restrict__ Wv,
    void* __restrict__ d0, void* __restrict__ d1,
    void* __restrict__ d2, void* __restrict__ d3, int mode) {
  __shared__ unsigned short lds2[2][32768];   // 2 x 64KB

  const int tid = threadIdx.x;
  const int wid = tid >> 6, l = tid & 63;
  const int wm = wid >> 2, wn = wid & 3;      // 2M x 4N wave grid; wave tile 128x64
  const int fr = l & 15, fg = l >> 4;
  const int swz = (fr & 7) << 3;              // frag-read XOR (shorts)

  // XCD-chunked swizzle (grid % 8 == 0)
  const int cpx = gridDim.x >> 3;
  int wg = ((int)blockIdx.x & 7) * cpx + ((int)blockIdx.x >> 3);

  const unsigned short* A = Aq;
  const unsigned short* W = Wq;
  int emode = mode;
  if (mode == 10) {
    int mat = wg / 192; wg -= mat * 192;
    if (mat == 0)      { emode = 0; }
    else if (mat == 1) { emode = 3; A = Akv; W = Wk; }
    else               { emode = 1; A = Akv; W = Wv; }
  }
  const int bm = wg >> 3, bn = wg & 7;        // N=2048 -> 8 col tiles of 256

  // staging source (pre-swizzled k-chunk so linear DMA lands in swizzled slots)
  const int lr = l >> 3;                       // row within 8-row block
  const int kc = (l & 7) ^ lr;                 // swizzled 8-elem k-chunk
  const unsigned short* gaBase = A + (size_t)(bm * 256 + wid * 16 + lr) * 2048 + kc * 8;
  const unsigned short* gbBase = W + (size_t)(bn * 256 + wid * 16 + lr) * 2048 + kc * 8;

#define STAGEA(Lp, kt) do {                                        \
    unsigned short* _d = (Lp) + wid * 1024;                        \
    const unsigned short* _s = gaBase + (size_t)(kt) * 64;         \
    gload_lds16(_s,               _d);                             \
    gload_lds16(_s + 8 * 2048,    _d + 512);                       \
    gload_lds16(_s + 128 * 2048,  _d + 8192);                      \
    gload_lds16(_s + 136 * 2048,  _d + 8704);                      \
  } while (0)
#define STAGEB(Lp, kt) do {                                        \
    unsigned short* _d = (Lp) + 16384 + wid * 1024;                \
    const unsigned short* _s = gbBase + (size_t)(kt) * 64;         \
    gload_lds16(_s,               _d);                             \
    gload_lds16(_s + 8 * 2048,    _d + 512);                       \
    gload_lds16(_s + 128 * 2048,  _d + 8192);                      \
    gload_lds16(_s + 136 * 2048,  _d + 8704);                      \
  } while (0)

  f32x4 acc[8][4] = {};
  bf16x8 af[8][2], bf01[2][2], bf23[2][2];

  // prologue: tiles 0 (buf0) and 1 (buf1); wait tile0, keep tile1 in flight
  STAGEA(&lds2[0][0], 0); STAGEB(&lds2[0][0], 0);
  STAGEA(&lds2[1][0], 1); STAGEB(&lds2[1][0], 1);
  asm volatile("s_waitcnt vmcnt(8)" ::: "memory");
  __builtin_amdgcn_s_barrier();

  for (int t = 0; t < 32; ++t) {
    unsigned short* Lp = &lds2[t & 1][0];
    const unsigned short* Ab = Lp + wm * 8192;
    const unsigned short* Bb = Lp + 16384 + (wn >> 1) * 8192 + (wn & 1) * 4096;

    // ---- phase 0: read A mi0-3 + B ni0-1; MFMA quad (mi0-3 x ni0-1) ----
#pragma unroll
    for (int mi = 0; mi < 4; ++mi)
#pragma unroll
      for (int ks = 0; ks < 2; ++ks)
        af[mi][ks] = *(const bf16x8*)&Ab[(mi * 16 + fr) * 64 + ((ks * 32 + fg * 8) ^ swz)];
#pragma unroll
    for (int ni = 0; ni < 2; ++ni)
#pragma unroll
      for (int ks = 0; ks < 2; ++ks)
        bf01[ni][ks] = *(const bf16x8*)&Bb[(ni * 16 + fr) * 64 + ((ks * 32 + fg * 8) ^ swz)];
    __builtin_amdgcn_s_setprio(1);
#pragma unroll
    for (int mi = 0; mi < 4; ++mi)
#pragma unroll
      for (int ni = 0; ni < 2; ++ni)
#pragma unroll
        for (int ks = 0; ks < 2; ++ks)
          acc[mi][ni] = MFMA16(af[mi][ks], bf01[ni][ks], acc[mi][ni]);
    __builtin_amdgcn_s_setprio(0);

    // ---- phase 1: read A mi4-7; MFMA quad (mi4-7 x ni0-1); barrier = A consumed ----
#pragma unroll
    for (int mi = 4; mi < 8; ++mi)
#pragma unroll
      for (int ks = 0; ks < 2; ++ks)
        af[mi][ks] = *(const bf16x8*)&Ab[(mi * 16 + fr) * 64 + ((ks * 32 + fg * 8) ^ swz)];
    __builtin_amdgcn_s_setprio(1);
#pragma unroll
    for (int mi = 4; mi < 8; ++mi)
#pragma unroll
      for (int ni = 0; ni < 2; ++ni)
#pragma unroll
        for (int ks = 0; ks < 2; ++ks)
          acc[mi][ni] = MFMA16(af[mi][ks], bf01[ni][ks], acc[mi][ni]);
    __builtin_amdgcn_s_setprio(0);
    __builtin_amdgcn_s_barrier();

    // ---- phase 2: read B ni2-3; prefetch A(t+2) into this buf (A now free); MFMA ----
#pragma unroll
    for (int ni = 0; ni < 2; ++ni)
#pragma unroll
      for (int ks = 0; ks < 2; ++ks)
        bf23[ni][ks] = *(const bf16x8*)&Bb[((ni + 2) * 16 + fr) * 64 + ((ks * 32 + fg * 8) ^ swz)];
    if (t < 30) STAGEA(Lp, t + 2);
    __builtin_amdgcn_s_setprio(1);
#pragma unroll
    for (int mi = 0; mi < 4; ++mi)
#pragma unroll
      for (int ni = 0; ni < 2; ++ni)
#pragma unroll
        for (int ks = 0; ks < 2; ++ks)
          acc[mi][ni + 2] = MFMA16(af[mi][ks], bf23[ni][ks], acc[mi][ni + 2]);
    __builtin_amdgcn_s_setprio(0);
    __builtin_amdgcn_s_barrier();   // B consumed

    // ---- phase 3: prefetch B(t+2); MFMA quad (mi4-7 x ni2-3); counted vmcnt ----
    if (t < 30) STAGEB(Lp, t + 2);
    __builtin_amdgcn_s_setprio(1);
#pragma unroll
    for (int mi = 4; mi < 8; ++mi)
#pragma unroll
      for (int ni = 0; ni < 2; ++ni)
#pragma unroll
        for (int ks = 0; ks < 2; ++ks)
          acc[mi][ni + 2] = MFMA16(af[mi][ks], bf23[ni][ks], acc[mi][ni + 2]);
    __builtin_amdgcn_s_setprio(0);
    __builtin_amdgcn_sched_barrier(0);
    if (t < 30)       asm volatile("s_waitcnt vmcnt(8)" ::: "memory");
    else if (t == 30) asm volatile("s_waitcnt vmcnt(0)" ::: "memory");
    if (t < 31) __builtin_amdgcn_s_barrier();
  }
#undef STAGEA
#undef STAGEB

  // ---- epilogue ----
#pragma unroll
  for (int mi = 0; mi < 8; ++mi) {
    const int row0 = bm * 256 + wm * 128 + mi * 16 + fg * 4;
    if (emode == 1) {
      // V: 4 s-contiguous values per (mi,ni) -> one 8B store (swizzle preserves runs)
      int b = row0 / 3072, s0 = row0 - b * 3072;
#pragma unroll
      for (int ni = 0; ni < 4; ++ni) {
        int col = bn * 256 + wn * 64 + ni * 16 + fr;
        int hh = col >> 7, d = col & 127;
        size_t bh = (size_t)(b * NH + hh);
        size_t idx = (bh * 128 + d) * (size_t)3072 + ((s0 & ~31) | ((s0 & 31) ^ ((d & 3) << 3)));
        uint2 pk;
        pk.x = cvtpk(acc[mi][ni][0], acc[mi][ni][1]);
        pk.y = cvtpk(acc[mi][ni][2], acc[mi][ni][3]);
        *(uint2*)((unsigned short*)d3 + idx) = pk;
      }
    } else {
#pragma unroll
      for (int r = 0; r < 4; ++r) {
        int row = row0 + r;
#pragma unroll
        for (int ni = 0; ni < 4; ++ni) {
          int col = bn * 256 + wn * 64 + ni * 16 + fr;
          float v = acc[mi][ni][r];
          if (emode == 2) {
            ((float*)d0)[(size_t)row * 2048 + col] = v;   // d_out is FLOAT32
          } else if (emode == 0) {
            int hh = col >> 7, d = col & 127;
            if (row < 4096) {
              int b = row >> 11, s = row & 2047;
              ((unsigned short*)d0)[((size_t)(b * NH + hh) * 2048 + s) * 128 + d] = f2bf(v);
            } else {
              int rr = row - 4096, b = rr >> 10, s = rr & 1023;
              ((unsigned short*)d1)[((size_t)(b * NH + hh) * 1024 + s) * 128 + d] = f2bf(v);
            }
          } else {  // emode == 3 : K, d-swizzled
            int b = row / 3072, s = row - b * 3072;
            int hh = col >> 7, d = col & 127;
            size_t bh = (size_t)(b * NH + hh);
            ((unsigned short*)d2)[(bh * 3072 + s) * 128 + (d ^ ((s & 7) << 3))] = f2bf(v);
          }
        }
      }
    }
  }
}

// ---------------- flash attention: dbuf K/V, KVBLK=32, counted-vmcnt -------------
// grid 768 (XCD-chunked). 4 waves x 32 q. LDS: Ks[2]|Vs[2]|P = 40KB.
__global__ __launch_bounds__(256, 3) void attn_kernel(
    const unsigned short* __restrict__ Qt, const unsigned short* __restrict__ Qi,
    const unsigned short* __restrict__ Kh, const unsigned short* __restrict__ Vt,
    unsigned short* __restrict__ AOt, unsigned short* __restrict__ AOi) {
  __shared__ unsigned short Sh[20480];  // Ks0|Ks1|Vs0|Vs1|P(4x1024)

  const int lin = blockIdx.x;
  const int w768 = (lin & 7) * 96 + (lin >> 3);
  const int qt24 = w768 % 24;
  const int hb   = w768 / 24;
  const int h = hb & 15, b = hb >> 4;
  const bool is_text = qt24 < 16;
  const int qt = is_text ? qt24 : qt24 - 16;
  const int Sq = is_text ? 2048 : 1024;
  const unsigned short* Qh = is_text ? Qt : Qi;
  unsigned short* AO = is_text ? AOt : AOi;

  const int tid = threadIdx.x;
  const int w = tid >> 6, l = tid & 63;
  const int fr = l & 15, fg = l >> 4;
  const size_t bh = (size_t)(b * NH + h);
  unsigned short* Pw = Sh + 16384 + w * 1024;   // per-wave [32 q][32 k]

  const unsigned short* Qbase = Qh + (bh * Sq + (size_t)qt * 128 + w * 32) * HD;
  bf16x8 qf[2][4];
#pragma unroll
  for (int h2 = 0; h2 < 2; ++h2)
#pragma unroll
    for (int c = 0; c < 4; ++c)
      qf[h2][c] = *(const bf16x8*)(Qbase + (h2 * 16 + fr) * HD + c * 32 + fg * 8);

  f32x4 o[2][8] = {};
  float m[2]    = {-1e30f, -1e30f};
  float lsum[2] = {0.f, 0.f};

  const unsigned short* Kb = Kh + bh * (size_t)SKV * HD;
  const unsigned short* Vb = Vt + bh * (size_t)HD * SKV;

  const int swk = (fr & 7) << 3;   // K d-swizzle (within 128)
  const int swv = (fr & 3) << 3;   // V s-swizzle (within 32) + P swizzle

#define STAGE_K(kt, half) do {                                                   \
    unsigned short* _d = Sh + (half) * 4096 + w * 1024;                          \
    const unsigned short* _s = Kb + (size_t)((kt) * 32 + w * 8 + (l >> 4)) * 128 \
                               + (l & 15) * 8;                                   \
    gload_lds16(_s, _d);                                                         \
    gload_lds16(_s + 4 * 128, _d + 512);                                         \
  } while (0)
#define STAGE_V(kt, half) do {                                                   \
    unsigned short* _d = Sh + 8192 + (half) * 4096 + w * 1024;                   \
    const unsigned short* _s = Vb + (size_t)(w * 32 + (l >> 2)) * SKV            \
                               + (kt) * 32 + (l & 3) * 8;                        \
    gload_lds16(_s, _d);                                                         \
    gload_lds16(_s + 16 * SKV, _d + 512);                                        \
  } while (0)

  STAGE_K(0, 0);
  for (int kt = 0; kt < 96; ++kt) {
    const int half = kt & 1;
    STAGE_V(kt, half);
    asm volatile("s_waitcnt vmcnt(2)" ::: "memory");   // K(kt) ready; V(kt) in flight
    __builtin_amdgcn_s_barrier();

    const unsigned short* Ksc = Sh + half * 4096;
    f32x4 sT[2][2] = {};
#pragma unroll
    for (int j = 0; j < 2; ++j) {
      const int krb = (j * 16 + fr) * 128;
#pragma unroll
      for (int c = 0; c < 4; ++c) {
        bf16x8 kf = *(const bf16x8*)&Ksc[krb + ((c * 32 + fg * 8) ^ swk)];
        sT[0][j] = MFMA16(kf, qf[0][c], sT[0][j]);
        sT[1][j] = MFMA16(kf, qf[1][c], sT[1][j]);
      }
    }
    if (kt < 95) STAGE_K(kt + 1, half ^ 1);

#pragma unroll
    for (int h2 = 0; h2 < 2; ++h2) {
      float tm = fmaxf(fmaxf(fmaxf(sT[h2][0][0], sT[h2][0][1]),
                             fmaxf(sT[h2][0][2], sT[h2][0][3])),
                       fmaxf(fmaxf(sT[h2][1][0], sT[h2][1][1]),
                             fmaxf(sT[h2][1][2], sT[h2][1][3])));
      tm = fmaxf(tm, __shfl_xor(tm, 16));
      tm = fmaxf(tm, __shfl_xor(tm, 32));
      if (__any(tm - m[h2] > DEFER_THR)) {
        float mn = fmaxf(m[h2], tm);
        float al = exp2hw(m[h2] - mn);
#pragma unroll
        for (int nt = 0; nt < 8; ++nt) {
          f32x4 t = o[h2][nt];
          t[0] *= al; t[1] *= al; t[2] *= al; t[3] *= al;
          o[h2][nt] = t;
        }
        lsum[h2] *= al;
        m[h2] = mn;
      }
      const float mm = m[h2];
      float p00 = exp2hw(sT[h2][0][0] - mm), p01 = exp2hw(sT[h2][0][1] - mm);
      float p02 = exp2hw(sT[h2][0][2] - mm), p03 = exp2hw(sT[h2][0][3] - mm);
      float p10 = exp2hw(sT[h2][1][0] - mm), p11 = exp2hw(sT[h2][1][1] - mm);
      float p12 = exp2hw(sT[h2][1][2] - mm), p13 = exp2hw(sT[h2][1][3] - mm);
      lsum[h2] += (p00 + p01 + p02 + p03) + (p10 + p11 + p12 + p13);
      unsigned short* prow = &Pw[(h2 * 16 + fr) * 32];
      uint2 w0; w0.x = cvtpk(p00, p01); w0.y = cvtpk(p02, p03);
      uint2 w1; w1.x = cvtpk(p10, p11); w1.y = cvtpk(p12, p13);
      *(uint2*)(prow + ((fg * 4) ^ swv))      = w0;
      *(uint2*)(prow + ((16 + fg * 4) ^ swv)) = w1;
    }

    if (kt < 95) asm volatile("s_waitcnt vmcnt(2)" ::: "memory");  // V(kt) ready
    else         asm volatile("s_waitcnt vmcnt(0)" ::: "memory");
    __builtin_amdgcn_s_barrier();

    asm volatile("s_waitcnt lgkmcnt(0)" ::: "memory");
    __builtin_amdgcn_sched_barrier(0);

    const unsigned short* Vsc = Sh + 8192 + half * 4096;
    bf16x8 pb[2];
#pragma unroll
    for (int h2 = 0; h2 < 2; ++h2)
      pb[h2] = *(const bf16x8*)&Pw[(h2 * 16 + fr) * 32 + ((fg * 8) ^ swv)];
#pragma unroll
    for (int nt = 0; nt < 8; ++nt) {
      bf16x8 vf = *(const bf16x8*)&Vsc[(nt * 16 + fr) * 32 + ((fg * 8) ^ swv)];
      o[0][nt] = MFMA16(vf, pb[0], o[0][nt]);
      o[1][nt] = MFMA16(vf, pb[1], o[1][nt]);
    }
    __builtin_amdgcn_s_barrier();
  }
#undef STAGE_K
#undef STAGE_V

  float inv[2];
#pragma unroll
  for (int h2 = 0; h2 < 2; ++h2) {
    float t = lsum[h2];
    t += __shfl_xor(t, 16);
    t += __shfl_xor(t, 32);
    inv[h2] = 1.0f / t;
  }
  unsigned short* Os = &Sh[w * 4096];
#pragma unroll
  for (int h2 = 0; h2 < 2; ++h2) {
    unsigned short* orow = &Os[(h2 * 16 + fr) * 128];
    const int sw8 = (fr & 7) << 3;
#pragma unroll
    for (int nt = 0; nt < 8; ++nt) {
      uint2 pk;
      pk.x = cvtpk(o[h2][nt][0] * inv[h2], o[h2][nt][1] * inv[h2]);
      pk.y = cvtpk(o[h2][nt][2] * inv[h2], o[h2][nt][3] * inv[h2]);
      *(uint2*)(orow + ((nt * 16 + fg * 4) ^ sw8)) = pk;
    }
  }
  asm volatile("s_waitcnt lgkmcnt(0)" ::: "memory");
  __builtin_amdgcn_sched_barrier(0);
  const int qr4 = l >> 4;
  const int dc = (l & 15) * 8;
  unsigned short* AObase = AO + ((size_t)b * Sq + (size_t)qt * 128 + w * 32) * D_MODEL + h * HD;
#pragma unroll
  for (int g = 0; g < 8; ++g) {
    const int row = g * 4 + qr4;
    bf16x8 v = *reinterpret_cast<const bf16x8*>(&Os[row * 128 + (dc ^ ((row & 7) << 3))]);
    *reinterpret_cast<bf16x8*>(&AObase[(size_t)row * D_MODEL + dc]) = v;
  }
}

// ---------------- host launch ----------------
extern "C" void kernel_launch(void* const* d_in, const int* in_sizes, int n_in,
                              void* d_out, int out_size, void* d_ws, size_t ws_size,
                              hipStream_t stream) {
  const float* q_text  = (const float*)d_in[0];
  const float* q_image = (const float*)d_in[1];
  const float* k_text  = (const float*)d_in[2];
  const float* k_image = (const float*)d_in[3];
  const float* Wq = (const float*)d_in[4];
  const float* Wk = (const float*)d_in[5];
  const float* Wv = (const float*)d_in[6];
  const float* Wo = (const float*)d_in[7];
  const float* ln_tg = (const float*)d_in[8];
  const float* ln_tb = (const float*)d_in[9];
  const float* ln_ig = (const float*)d_in[10];
  const float* ln_ib = (const float*)d_in[11];

  // workspace layout (bf16 elements)
  unsigned short* wq  = (unsigned short*)d_ws;
  unsigned short* wk  = wq  + 4194304;
  unsigned short* wv  = wk  + 4194304;
  unsigned short* wo  = wv  + 4194304;
  unsigned short* xqt = wo  + 4194304;   // LN'd q_text  [4096,2048]; later AO_text
  unsigned short* xqi = xqt + 8388608;   // LN'd q_image [2048,2048]; later AO_image
  unsigned short* xk  = xqi + 4194304;   // LN'd concat k [2,3072,2048]
  unsigned short* qht = xk  + 12582912;  // [2,16,2048,128]
  unsigned short* qhi = qht + 8388608;   // [2,16,1024,128]
  unsigned short* kh  = qhi + 4194304;   // [2,16,3072,128] (d-swizzled)
  unsigned short* vt  = kh  + 12582912;  // [2,16,128,3072] (s-swizzled, 32-groups)
  const size_t needed = (size_t)(vt + 12582912 - wq) * 2;
  if (ws_size < needed) return;

  cvt_w_kernel<<<dim3(2048, 4), 256, 0, stream>>>(Wq, Wk, Wv, Wo, wq);

  ln_kernel<<<4096, 256, 0, stream>>>(q_text,  ln_tg, ln_tb, xqt, 2048, 2048, 0);
  ln_kernel<<<2048, 256, 0, stream>>>(q_image, ln_ig, ln_ib, xqi, 1024, 1024, 0);
  ln_kernel<<<4096, 256, 0, stream>>>(k_text,  ln_tg, ln_tb, xk, 2048, 3072, 0);
  ln_kernel<<<2048, 256, 0, stream>>>(k_image, ln_ig, ln_ib, xk, 1024, 3072, 2048);

  // Q+K+V in ONE dispatch: 576 tiles of 256^2
  gemm256p_kernel<<<576, 512, 0, stream>>>(xqt, xk, wq, wk, wv, qht, qhi, kh, vt, 10);

  attn_kernel<<<768, 256, 0, stream>>>(qht, qhi, kh, vt, xqt, xqi);

  // out projection: 192 tiles, f32 straight into d_out
  gemm256p_kernel<<<192, 512, 0, stream>>>(xqt, nullptr, wo, nullptr, nullptr,
                                           d_out, nullptr, nullptr, nullptr, 2);
}